// Round 1
// baseline (8857.096 us; speedup 1.0000x reference)
//
#include <hip/hip_runtime.h>

typedef unsigned short u16;
typedef unsigned int u32;
typedef __bf16 bf16x8 __attribute__((ext_vector_type(8)));
typedef float f32x4 __attribute__((ext_vector_type(4)));

#define B_ 8
#define HOR_ 10
#define P_ 16
#define NO_ 128
#define NR_ 8
#define TPS_ 136
#define T_ 1376
#define D_ 768
#define NH_ 12
#define HD_ 64
#define F_ 3072
#define L_ 12
#define BT_ (B_*T_)   /* 11008 */

__device__ __forceinline__ float bf2f(u16 u){ return __uint_as_float(((u32)u)<<16); }
__device__ __forceinline__ u16 f2bf(float f){
  u32 x = __float_as_uint(f);
  u32 r = (x + 0x7fffu + ((x>>16)&1u)) >> 16;
  return (u16)r;
}

// async global->LDS, 16B per lane
__device__ __forceinline__ void gl_lds16(const u16* g, u16* l){
  __builtin_amdgcn_global_load_lds((const __attribute__((address_space(1))) void*)g,
                                   (__attribute__((address_space(3))) void*)l,
                                   16, 0, 0);
}

// ---------------------------------------------------------------- dtype probe
// flag=1 -> inputs are fp32; flag=0 -> inputs are bf16.
__global__ __launch_bounds__(256) void detect_k(const u16* __restrict__ w, int* __restrict__ flag){
  int tid = threadIdx.x;
  int bad = 0;
  for (int i = tid; i < 8192; i += 256){
    int e = (w[i] >> 7) & 0xFF;
    bad += (e >= 0xF0);
  }
  #pragma unroll
  for (int m=1;m<64;m<<=1) bad += __shfl_xor(bad, m, 64);
  __shared__ int s[4];
  if ((tid & 63) == 0) s[tid>>6] = bad;
  __syncthreads();
  if (tid == 0) flag[0] = (s[0]+s[1]+s[2]+s[3] > 4) ? 1 : 0;
}

// ---------------------------------------------------------------- canonicalize any float tensor -> bf16
__global__ __launch_bounds__(256) void conv_k(const void* __restrict__ src, u16* __restrict__ dst,
                                              int n, const int* __restrict__ flag){
  int f = flag[0];
  int stride = gridDim.x * 256;
  int i0 = blockIdx.x*256 + threadIdx.x;
  if (f){
    const float* s = (const float*)src;
    for (int i = i0; i < n; i += stride) dst[i] = f2bf(s[i]);
  } else {
    const u16* s = (const u16*)src;
    for (int i = i0; i < n; i += stride) dst[i] = s[i];
  }
}

// ---------------------------------------------------------------- convert + transpose weights [L][K][N] -> bf16 [L][N][K]
__global__ __launch_bounds__(256) void convT_k(const void* __restrict__ src, u16* __restrict__ dst,
                                               int K, int N, const int* __restrict__ flag){
  __shared__ u16 t[32][33];
  int f = flag[0];
  size_t so = (size_t)blockIdx.z * K * N;
  size_t dz = (size_t)blockIdx.z * N * K;
  int k0 = blockIdx.y*32, n0 = blockIdx.x*32;
  int tid = threadIdx.x;
  int tx = tid & 31, ty = tid >> 5;   // ty in [0,8)
  #pragma unroll
  for (int r=0;r<32;r+=8){
    int k = k0 + ty + r, n = n0 + tx;
    u16 bv;
    if (f) bv = f2bf(((const float*)src)[so + (size_t)k*N + n]);
    else   bv = ((const u16*)src)[so + (size_t)k*N + n];
    t[ty+r][tx] = bv;
  }
  __syncthreads();
  #pragma unroll
  for (int r=0;r<32;r+=8){
    int n = n0 + ty + r, k = k0 + tx;
    dst[dz + (size_t)n*K + k] = t[tx][ty+r];
  }
}

// ---------------------------------------------------------------- init h (fp32 residual) from canonical bf16 tokens
__global__ __launch_bounds__(256) void init_h(const u16* __restrict__ pre, const u16* __restrict__ obs,
                                              const u16* __restrict__ ro, float* __restrict__ h){
  int bt = blockIdx.x; int b = bt / T_; int t = bt - b*T_;
  const u16* src;
  if (t < P_) src = pre + ((size_t)(b*P_ + t))*D_;
  else {
    int u = t - P_; int ts = u / TPS_; int r = u - ts*TPS_;
    if (r < NO_) src = obs + ((size_t)((b*HOR_ + ts)*NO_ + r))*D_;
    else         src = ro  + ((size_t)((b*HOR_ + ts)*NR_ + (r - NO_)))*D_;
  }
  float* dst = h + (size_t)bt*D_;
  for (int d = threadIdx.x; d < D_; d += 256) dst[d] = bf2f(src[d]);
}

// ---------------------------------------------------------------- LayerNorm: fp32 h -> bf16 y
__global__ __launch_bounds__(256) void ln_k(const float* __restrict__ h, const u16* __restrict__ s,
                                            const u16* __restrict__ bia, u16* __restrict__ y){
  int row = blockIdx.x;
  const float* x = h + (size_t)row*D_;
  int tid = threadIdx.x;
  float v0 = x[tid], v1 = x[tid+256], v2 = x[tid+512];
  float sum = v0+v1+v2;
  float sq  = v0*v0+v1*v1+v2*v2;
  #pragma unroll
  for (int m=1;m<64;m<<=1){ sum += __shfl_xor(sum,m,64); sq += __shfl_xor(sq,m,64); }
  __shared__ float ls[4], lq[4];
  int w = tid>>6;
  if ((tid&63)==0){ ls[w]=sum; lq[w]=sq; }
  __syncthreads();
  sum = ls[0]+ls[1]+ls[2]+ls[3];
  sq  = lq[0]+lq[1]+lq[2]+lq[3];
  float mu  = sum * (1.0f/D_);
  float var = sq * (1.0f/D_) - mu*mu;
  float rstd = rsqrtf(fmaxf(var, 0.f) + 1e-6f);
  u16* yo = y + (size_t)row*D_;
  yo[tid]     = f2bf((v0-mu)*rstd*bf2f(s[tid])     + bf2f(bia[tid]));
  yo[tid+256] = f2bf((v1-mu)*rstd*bf2f(s[tid+256]) + bf2f(bia[tid+256]));
  yo[tid+512] = f2bf((v2-mu)*rstd*bf2f(s[tid+512]) + bf2f(bia[tid+512]));
}

// ---------------------------------------------------------------- final LayerNorm: dual-dtype output
__global__ __launch_bounds__(256) void ln_out_k(const float* __restrict__ h, const u16* __restrict__ s,
                                                const u16* __restrict__ bia, void* __restrict__ out,
                                                const int* __restrict__ flag){
  int row = blockIdx.x;
  const float* x = h + (size_t)row*D_;
  int tid = threadIdx.x;
  float v0 = x[tid], v1 = x[tid+256], v2 = x[tid+512];
  float sum = v0+v1+v2;
  float sq  = v0*v0+v1*v1+v2*v2;
  #pragma unroll
  for (int m=1;m<64;m<<=1){ sum += __shfl_xor(sum,m,64); sq += __shfl_xor(sq,m,64); }
  __shared__ float ls[4], lq[4];
  int w = tid>>6;
  if ((tid&63)==0){ ls[w]=sum; lq[w]=sq; }
  __syncthreads();
  sum = ls[0]+ls[1]+ls[2]+ls[3];
  sq  = lq[0]+lq[1]+lq[2]+lq[3];
  float mu  = sum * (1.0f/D_);
  float var = sq * (1.0f/D_) - mu*mu;
  float rstd = rsqrtf(fmaxf(var, 0.f) + 1e-6f);
  float o0 = (v0-mu)*rstd*bf2f(s[tid])     + bf2f(bia[tid]);
  float o1 = (v1-mu)*rstd*bf2f(s[tid+256]) + bf2f(bia[tid+256]);
  float o2 = (v2-mu)*rstd*bf2f(s[tid+512]) + bf2f(bia[tid+512]);
  if (flag[0]){
    float* fo = (float*)out + (size_t)row*D_;
    fo[tid] = o0; fo[tid+256] = o1; fo[tid+512] = o2;
  } else {
    u16* bo = (u16*)out + (size_t)row*D_;
    bo[tid] = f2bf(o0); bo[tid+256] = f2bf(o1); bo[tid+512] = f2bf(o2);
  }
}

// ---------------------------------------------------------------- GEMM 128x128 tile, BK=32, mfma 16x16x32 bf16
// W is PRE-TRANSPOSED: [N][K] row-major -> both A and B tiles stage linearly
// via global_load_lds (no VALU packing, no explicit ds_write).
// EPI: 0 = QKV scatter (q,k layout [bh][t][hd]; v transposed [bh][hd][t])
//      1 = residual add into fp32 h
//      2 = gelu -> bf16 u
template<int EPI>
__global__ __launch_bounds__(256) void gemm_k(
    const u16* __restrict__ A, const u16* __restrict__ W, const u16* __restrict__ bias,
    int N, int K,
    u16* __restrict__ qo, u16* __restrict__ ko, u16* __restrict__ vto,
    float* __restrict__ hres, u16* __restrict__ uo)
{
  __shared__ alignas(16) u16 Alds[128*32];
  __shared__ alignas(16) u16 Blds[128*32];
  int tid = threadIdx.x;
  int bn = blockIdx.x*128, bm = blockIdx.y*128;
  int lane = tid & 63, wv = tid >> 6;
  int l15 = lane & 15, quad = lane >> 4;
  int wm = (wv & 1)*64, wn = (wv >> 1)*64;
  f32x4 acc[4][4];
  #pragma unroll
  for (int i=0;i<4;i++)
    #pragma unroll
    for (int j=0;j<4;j++)
      acc[i][j] = (f32x4){0.f,0.f,0.f,0.f};

  for (int k0 = 0; k0 < K; k0 += 32){
    // ---- stage A tile [128 m][32 k] and B tile [128 n][32 k], both linear pitch 32
    #pragma unroll
    for (int i=0;i<2;i++){
      int idx = tid + 256*i;
      int m = idx >> 2, oct = idx & 3;
      gl_lds16(A + (size_t)(bm+m)*K + k0 + oct*8, &Alds[idx*8]);
      gl_lds16(W + (size_t)(bn+m)*K + k0 + oct*8, &Blds[idx*8]);
    }
    __syncthreads();   // compiler drains vmcnt before s_barrier
    bf16x8 af[4], bfr[4];
    #pragma unroll
    for (int fm=0;fm<4;fm++) af[fm]  = *(const bf16x8*)&Alds[(wm + fm*16 + l15)*32 + quad*8];
    #pragma unroll
    for (int fn=0;fn<4;fn++) bfr[fn] = *(const bf16x8*)&Blds[(wn + fn*16 + l15)*32 + quad*8];
    #pragma unroll
    for (int fm=0;fm<4;fm++)
      #pragma unroll
      for (int fn=0;fn<4;fn++)
        acc[fm][fn] = __builtin_amdgcn_mfma_f32_16x16x32_bf16(af[fm], bfr[fn], acc[fm][fn], 0,0,0);
    __syncthreads();
  }

  // ---- epilogue: C row = bm+wm+fm*16+quad*4+r, col = bn+wn+fn*16+l15
  #pragma unroll
  for (int fn=0;fn<4;fn++){
    int col = bn + wn + fn*16 + l15;
    float bv = bf2f(bias[col]);
    int which=0, hh=0, hd=0;
    if (EPI==0){ which = col/768; int rem = col - which*768; hh = rem>>6; hd = rem&63; }
    #pragma unroll
    for (int fm=0;fm<4;fm++){
      int row0 = bm + wm + fm*16 + quad*4;
      #pragma unroll
      for (int r=0;r<4;r++){
        int row = row0 + r;
        float val = acc[fm][fn][r] + bv;
        if (EPI==0){
          int b = row / T_; int t = row - b*T_;
          int bh = b*NH_ + hh;
          u16 ob = f2bf(val);
          if (which==0)      qo[((size_t)bh*T_ + t)*HD_ + hd] = ob;
          else if (which==1) ko[((size_t)bh*T_ + t)*HD_ + hd] = ob;
          else               vto[((size_t)bh*HD_ + hd)*T_ + t] = ob;
        } else if (EPI==1){
          hres[(size_t)row*D_ + col] += val;
        } else {
          float xx = val;
          float g = 0.5f*xx*(1.0f + tanhf(0.7978845608028654f*(xx + 0.044715f*xx*xx*xx)));
          uo[(size_t)row*F_ + col] = f2bf(g);
        }
      }
    }
  }
}

// ---------------------------------------------------------------- rule mask helpers
__device__ __forceinline__ void tok_meta(int t, int& g, int& ts){
  if (t < P_){ g = 0; ts = -1; }
  else { int u = t - P_; ts = u / TPS_; int r = u - ts*TPS_; g = (r < NO_) ? 1 : 2; }
}
__device__ __forceinline__ bool allowed(int qg, int qts, int kg, int kts){
  if (kg == 0) return true;
  if (qg == 0) return false;
  if (kg == 1) return kts <= qts;
  return (qg == 2) && (kts <= qts);
}

// ---------------------------------------------------------------- flash attention: 1 wave, 32 q-rows, 32-key tiles
#define MASKVAL (-30000.0f)
__global__ __launch_bounds__(64) void attn_k(const u16* __restrict__ q, const u16* __restrict__ kk_,
                                             const u16* __restrict__ vt, u16* __restrict__ att){
  __shared__ alignas(16) u16 Plds[2][16*40];
  int lane = threadIdx.x;
  int l15 = lane & 15, quad = lane >> 4;
  int bh = blockIdx.y;
  int b = bh / NH_, h = bh - b*NH_;
  int qbase = blockIdx.x * 32;
  const u16* Qb = q   + (size_t)bh*T_*HD_;
  const u16* Kb = kk_ + (size_t)bh*T_*HD_;
  const u16* Vb = vt  + (size_t)bh*HD_*T_;

  bf16x8 qa[2][2];
  #pragma unroll
  for (int mi=0;mi<2;mi++)
    #pragma unroll
    for (int c=0;c<2;c++)
      qa[mi][c] = *(const bf16x8*)(Qb + (size_t)(qbase + mi*16 + l15)*HD_ + c*32 + quad*8);

  f32x4 o[2][4];
  float m_[2][4], l_[2][4];
  int qg[2][4], qts[2][4];
  #pragma unroll
  for (int mi=0;mi<2;mi++){
    #pragma unroll
    for (int fn=0;fn<4;fn++) o[mi][fn] = (f32x4){0.f,0.f,0.f,0.f};
    #pragma unroll
    for (int r=0;r<4;r++){
      m_[mi][r] = MASKVAL; l_[mi][r] = 0.f;
      tok_meta(qbase + mi*16 + quad*4 + r, qg[mi][r], qts[mi][r]);
    }
  }

  int ts_max = (qbase + 31 - P_) / TPS_;
  int kend = (P_ + (ts_max+1)*TPS_ + 31) / 32;

  for (int kt = 0; kt < kend; kt++){
    int kbase = kt*32;
    bf16x8 kb[2][2];
    #pragma unroll
    for (int hf=0;hf<2;hf++)
      #pragma unroll
      for (int c=0;c<2;c++)
        kb[hf][c] = *(const bf16x8*)(Kb + (size_t)(kbase + hf*16 + l15)*HD_ + c*32 + quad*8);

    f32x4 sacc[2][2];
    #pragma unroll
    for (int mi=0;mi<2;mi++)
      #pragma unroll
      for (int hf=0;hf<2;hf++){
        f32x4 z = (f32x4){0.f,0.f,0.f,0.f};
        z = __builtin_amdgcn_mfma_f32_16x16x32_bf16(qa[mi][0], kb[hf][0], z, 0,0,0);
        z = __builtin_amdgcn_mfma_f32_16x16x32_bf16(qa[mi][1], kb[hf][1], z, 0,0,0);
        sacc[mi][hf] = z;
      }

    int kg0, kts0, kg1, kts1;
    tok_meta(kbase + l15,      kg0, kts0);
    tok_meta(kbase + 16 + l15, kg1, kts1);

    #pragma unroll
    for (int mi=0;mi<2;mi++){
      #pragma unroll
      for (int r=0;r<4;r++){
        float s0 = allowed(qg[mi][r], qts[mi][r], kg0, kts0) ? sacc[mi][0][r]*0.125f : MASKVAL;
        float s1 = allowed(qg[mi][r], qts[mi][r], kg1, kts1) ? sacc[mi][1][r]*0.125f : MASKVAL;
        float rm = fmaxf(s0, s1);
        #pragma unroll
        for (int m=1;m<16;m<<=1) rm = fmaxf(rm, __shfl_xor(rm, m, 64));
        float mprev = m_[mi][r];
        float mnew = fmaxf(mprev, rm);
        float p0 = __expf(s0 - mnew);
        float p1 = __expf(s1 - mnew);
        float rs = p0 + p1;
        #pragma unroll
        for (int m=1;m<16;m<<=1) rs += __shfl_xor(rs, m, 64);
        float alpha = __expf(mprev - mnew);
        l_[mi][r] = l_[mi][r]*alpha + rs;
        m_[mi][r] = mnew;
        #pragma unroll
        for (int fn=0;fn<4;fn++) o[mi][fn][r] *= alpha;
        Plds[mi][(quad*4+r)*40 + l15]      = f2bf(p0);
        Plds[mi][(quad*4+r)*40 + 16 + l15] = f2bf(p1);
      }
    }
    __syncthreads();
    bf16x8 pa[2];
    #pragma unroll
    for (int mi=0;mi<2;mi++) pa[mi] = *(const bf16x8*)&Plds[mi][l15*40 + quad*8];
    #pragma unroll
    for (int fn=0;fn<4;fn++){
      bf16x8 vb = *(const bf16x8*)(Vb + (size_t)(fn*16 + l15)*T_ + kbase + quad*8);
      #pragma unroll
      for (int mi=0;mi<2;mi++)
        o[mi][fn] = __builtin_amdgcn_mfma_f32_16x16x32_bf16(pa[mi], vb, o[mi][fn], 0,0,0);
    }
    __syncthreads();
  }

  #pragma unroll
  for (int mi=0;mi<2;mi++)
    #pragma unroll
    for (int fn=0;fn<4;fn++)
      #pragma unroll
      for (int r=0;r<4;r++){
        int row = qbase + mi*16 + quad*4 + r;
        int d = fn*16 + l15;
        float val = o[mi][fn][r] / fmaxf(l_[mi][r], 1e-30f);
        att[((size_t)b*T_ + row)*D_ + h*HD_ + d] = f2bf(val);
      }
}

// ---------------------------------------------------------------- launch
extern "C" void kernel_launch(void* const* d_in, const int* in_sizes, int n_in,
                              void* d_out, int out_size, void* d_ws, size_t ws_size,
                              hipStream_t stream){
  char* p = (char*)d_ws;
  int* flag = (int*)p; p += 256;
  u16* c_pre  = (u16*)p; p += (size_t)98304*2;
  u16* c_obs  = (u16*)p; p += (size_t)7864320*2;
  u16* c_ro   = (u16*)p; p += (size_t)491520*2;
  u16* c_ln1s = (u16*)p; p += (size_t)9216*2;
  u16* c_ln1b = (u16*)p; p += (size_t)9216*2;
  u16* c_wqkv = (u16*)p; p += (size_t)21233664*2;
  u16* c_bqkv = (u16*)p; p += (size_t)27648*2;
  u16* c_wo   = (u16*)p; p += (size_t)7077888*2;
  u16* c_bo   = (u16*)p; p += (size_t)9216*2;
  u16* c_ln2s = (u16*)p; p += (size_t)9216*2;
  u16* c_ln2b = (u16*)p; p += (size_t)9216*2;
  u16* c_w1   = (u16*)p; p += (size_t)28311552*2;
  u16* c_b1   = (u16*)p; p += (size_t)36864*2;
  u16* c_w2   = (u16*)p; p += (size_t)28311552*2;
  u16* c_b2   = (u16*)p; p += (size_t)9216*2;
  u16* c_lnfs = (u16*)p; p += (size_t)768*2;
  u16* c_lnfb = (u16*)p; p += (size_t)768*2;
  float* h = (float*)p; p += (size_t)BT_*D_*4;
  u16* y   = (u16*)p;   p += (size_t)BT_*D_*2;
  u16* qb  = (u16*)p;   p += (size_t)BT_*D_*2;
  u16* kb  = (u16*)p;   p += (size_t)BT_*D_*2;
  u16* vtb = (u16*)p;   p += (size_t)BT_*D_*2;
  u16* ub  = (u16*)p;   p += (size_t)BT_*F_*2;
  u16* att = y;  // attn output reuses y (y dead after QKV gemm, rewritten by ln2)

  detect_k<<<1, 256, 0, stream>>>((const u16*)d_in[8], flag);

  auto cv = [&](const void* s, u16* d, int n){
    int g = (n + 2047) / 2048;
    conv_k<<<g, 256, 0, stream>>>(s, d, n, flag);
  };
  // non-weight tensors: plain convert
  cv(d_in[0],  c_pre,  98304);
  cv(d_in[2],  c_obs,  7864320);
  cv(d_in[4],  c_ro,   491520);
  cv(d_in[6],  c_ln1s, 9216);
  cv(d_in[7],  c_ln1b, 9216);
  cv(d_in[9],  c_bqkv, 27648);
  cv(d_in[11], c_bo,   9216);
  cv(d_in[12], c_ln2s, 9216);
  cv(d_in[13], c_ln2b, 9216);
  cv(d_in[15], c_b1,   36864);
  cv(d_in[17], c_b2,   9216);
  cv(d_in[18], c_lnfs, 768);
  cv(d_in[19], c_lnfb, 768);
  // weight matrices: convert + transpose [L][K][N] -> [L][N][K]
  auto cvT = [&](const void* s, u16* d, int Kd, int Nd){
    convT_k<<<dim3(Nd/32, Kd/32, L_), 256, 0, stream>>>(s, d, Kd, Nd, flag);
  };
  cvT(d_in[8],  c_wqkv, D_, 3*D_);
  cvT(d_in[10], c_wo,   D_, D_);
  cvT(d_in[14], c_w1,   D_, F_);
  cvT(d_in[16], c_w2,   F_, D_);

  init_h<<<BT_, 256, 0, stream>>>(c_pre, c_obs, c_ro, h);
  for (int l = 0; l < L_; l++){
    ln_k<<<BT_, 256, 0, stream>>>(h, c_ln1s + l*D_, c_ln1b + l*D_, y);
    gemm_k<0><<<dim3(18,86), 256, 0, stream>>>(y, c_wqkv + (size_t)l*D_*3*D_, c_bqkv + (size_t)l*3*D_,
                                               3*D_, D_, qb, kb, vtb, nullptr, nullptr);
    attn_k<<<dim3(43,96), 64, 0, stream>>>(qb, kb, vtb, att);
    gemm_k<1><<<dim3(6,86), 256, 0, stream>>>(att, c_wo + (size_t)l*D_*D_, c_bo + (size_t)l*D_,
                                              D_, D_, nullptr, nullptr, nullptr, h, nullptr);
    ln_k<<<BT_, 256, 0, stream>>>(h, c_ln2s + l*D_, c_ln2b + l*D_, y);
    gemm_k<2><<<dim3(24,86), 256, 0, stream>>>(y, c_w1 + (size_t)l*D_*F_, c_b1 + (size_t)l*F_,
                                               F_, D_, nullptr, nullptr, nullptr, nullptr, ub);
    gemm_k<1><<<dim3(6,86), 256, 0, stream>>>(ub, c_w2 + (size_t)l*F_*D_, c_b2 + (size_t)l*D_,
                                              D_, F_, nullptr, nullptr, nullptr, h, nullptr);
  }
  ln_out_k<<<BT_, 256, 0, stream>>>(h, c_lnfs, c_lnfb, d_out, flag);
}

// Round 2
// 7246.284 us; speedup vs baseline: 1.2223x; 1.2223x over previous
//
#include <hip/hip_runtime.h>

typedef unsigned short u16;
typedef unsigned int u32;
typedef __bf16 bf16x8 __attribute__((ext_vector_type(8)));
typedef float f32x4 __attribute__((ext_vector_type(4)));

#define B_ 8
#define HOR_ 10
#define P_ 16
#define NO_ 128
#define NR_ 8
#define TPS_ 136
#define T_ 1376
#define D_ 768
#define NH_ 12
#define HD_ 64
#define F_ 3072
#define L_ 12
#define BT_ (B_*T_)   /* 11008 */

__device__ __forceinline__ float bf2f(u16 u){ return __uint_as_float(((u32)u)<<16); }
__device__ __forceinline__ u16 f2bf(float f){
  u32 x = __float_as_uint(f);
  u32 r = (x + 0x7fffu + ((x>>16)&1u)) >> 16;
  return (u16)r;
}
__device__ __forceinline__ u32 pkbf(float a, float b){
  union { __bf16 h[2]; u32 w; } u;
  u.h[0] = (__bf16)a; u.h[1] = (__bf16)b;
  return u.w;
}

// async global->LDS, 16B per lane
__device__ __forceinline__ void gl_lds16(const u16* g, u16* l){
  __builtin_amdgcn_global_load_lds((const __attribute__((address_space(1))) void*)g,
                                   (__attribute__((address_space(3))) void*)l,
                                   16, 0, 0);
}

// ---------------------------------------------------------------- dtype probe
// flag=1 -> inputs are fp32; flag=0 -> inputs are bf16.
__global__ __launch_bounds__(256) void detect_k(const u16* __restrict__ w, int* __restrict__ flag){
  int tid = threadIdx.x;
  int bad = 0;
  for (int i = tid; i < 8192; i += 256){
    int e = (w[i] >> 7) & 0xFF;
    bad += (e >= 0xF0);
  }
  #pragma unroll
  for (int m=1;m<64;m<<=1) bad += __shfl_xor(bad, m, 64);
  __shared__ int s[4];
  if ((tid & 63) == 0) s[tid>>6] = bad;
  __syncthreads();
  if (tid == 0) flag[0] = (s[0]+s[1]+s[2]+s[3] > 4) ? 1 : 0;
}

// ---------------------------------------------------------------- canonicalize any float tensor -> bf16
__global__ __launch_bounds__(256) void conv_k(const void* __restrict__ src, u16* __restrict__ dst,
                                              int n, const int* __restrict__ flag){
  int f = flag[0];
  int stride = gridDim.x * 256;
  int i0 = blockIdx.x*256 + threadIdx.x;
  if (f){
    const float* s = (const float*)src;
    for (int i = i0; i < n; i += stride) dst[i] = f2bf(s[i]);
  } else {
    const u16* s = (const u16*)src;
    for (int i = i0; i < n; i += stride) dst[i] = s[i];
  }
}

// ---------------------------------------------------------------- convert + transpose weights [L][K][N] -> bf16 [L][N][K]
__global__ __launch_bounds__(256) void convT_k(const void* __restrict__ src, u16* __restrict__ dst,
                                               int K, int N, const int* __restrict__ flag){
  __shared__ u16 t[32][33];
  int f = flag[0];
  size_t so = (size_t)blockIdx.z * K * N;
  size_t dz = (size_t)blockIdx.z * N * K;
  int k0 = blockIdx.y*32, n0 = blockIdx.x*32;
  int tid = threadIdx.x;
  int tx = tid & 31, ty = tid >> 5;   // ty in [0,8)
  #pragma unroll
  for (int r=0;r<32;r+=8){
    int k = k0 + ty + r, n = n0 + tx;
    u16 bv;
    if (f) bv = f2bf(((const float*)src)[so + (size_t)k*N + n]);
    else   bv = ((const u16*)src)[so + (size_t)k*N + n];
    t[ty+r][tx] = bv;
  }
  __syncthreads();
  #pragma unroll
  for (int r=0;r<32;r+=8){
    int n = n0 + ty + r, k = k0 + tx;
    dst[dz + (size_t)n*K + k] = t[tx][ty+r];
  }
}

// ---------------------------------------------------------------- init h (fp32 residual) from canonical bf16 tokens
__global__ __launch_bounds__(256) void init_h(const u16* __restrict__ pre, const u16* __restrict__ obs,
                                              const u16* __restrict__ ro, float* __restrict__ h){
  int bt = blockIdx.x; int b = bt / T_; int t = bt - b*T_;
  const u16* src;
  if (t < P_) src = pre + ((size_t)(b*P_ + t))*D_;
  else {
    int u = t - P_; int ts = u / TPS_; int r = u - ts*TPS_;
    if (r < NO_) src = obs + ((size_t)((b*HOR_ + ts)*NO_ + r))*D_;
    else         src = ro  + ((size_t)((b*HOR_ + ts)*NR_ + (r - NO_)))*D_;
  }
  float* dst = h + (size_t)bt*D_;
  for (int d = threadIdx.x; d < D_; d += 256) dst[d] = bf2f(src[d]);
}

// ---------------------------------------------------------------- LayerNorm: fp32 h -> bf16 y
__global__ __launch_bounds__(256) void ln_k(const float* __restrict__ h, const u16* __restrict__ s,
                                            const u16* __restrict__ bia, u16* __restrict__ y){
  int row = blockIdx.x;
  const float* x = h + (size_t)row*D_;
  int tid = threadIdx.x;
  float v0 = x[tid], v1 = x[tid+256], v2 = x[tid+512];
  float sum = v0+v1+v2;
  float sq  = v0*v0+v1*v1+v2*v2;
  #pragma unroll
  for (int m=1;m<64;m<<=1){ sum += __shfl_xor(sum,m,64); sq += __shfl_xor(sq,m,64); }
  __shared__ float ls[4], lq[4];
  int w = tid>>6;
  if ((tid&63)==0){ ls[w]=sum; lq[w]=sq; }
  __syncthreads();
  sum = ls[0]+ls[1]+ls[2]+ls[3];
  sq  = lq[0]+lq[1]+lq[2]+lq[3];
  float mu  = sum * (1.0f/D_);
  float var = sq * (1.0f/D_) - mu*mu;
  float rstd = rsqrtf(fmaxf(var, 0.f) + 1e-6f);
  u16* yo = y + (size_t)row*D_;
  yo[tid]     = f2bf((v0-mu)*rstd*bf2f(s[tid])     + bf2f(bia[tid]));
  yo[tid+256] = f2bf((v1-mu)*rstd*bf2f(s[tid+256]) + bf2f(bia[tid+256]));
  yo[tid+512] = f2bf((v2-mu)*rstd*bf2f(s[tid+512]) + bf2f(bia[tid+512]));
}

// ---------------------------------------------------------------- final LayerNorm: dual-dtype output
__global__ __launch_bounds__(256) void ln_out_k(const float* __restrict__ h, const u16* __restrict__ s,
                                                const u16* __restrict__ bia, void* __restrict__ out,
                                                const int* __restrict__ flag){
  int row = blockIdx.x;
  const float* x = h + (size_t)row*D_;
  int tid = threadIdx.x;
  float v0 = x[tid], v1 = x[tid+256], v2 = x[tid+512];
  float sum = v0+v1+v2;
  float sq  = v0*v0+v1*v1+v2*v2;
  #pragma unroll
  for (int m=1;m<64;m<<=1){ sum += __shfl_xor(sum,m,64); sq += __shfl_xor(sq,m,64); }
  __shared__ float ls[4], lq[4];
  int w = tid>>6;
  if ((tid&63)==0){ ls[w]=sum; lq[w]=sq; }
  __syncthreads();
  sum = ls[0]+ls[1]+ls[2]+ls[3];
  sq  = lq[0]+lq[1]+lq[2]+lq[3];
  float mu  = sum * (1.0f/D_);
  float var = sq * (1.0f/D_) - mu*mu;
  float rstd = rsqrtf(fmaxf(var, 0.f) + 1e-6f);
  float o0 = (v0-mu)*rstd*bf2f(s[tid])     + bf2f(bia[tid]);
  float o1 = (v1-mu)*rstd*bf2f(s[tid+256]) + bf2f(bia[tid+256]);
  float o2 = (v2-mu)*rstd*bf2f(s[tid+512]) + bf2f(bia[tid+512]);
  if (flag[0]){
    float* fo = (float*)out + (size_t)row*D_;
    fo[tid] = o0; fo[tid+256] = o1; fo[tid+512] = o2;
  } else {
    u16* bo = (u16*)out + (size_t)row*D_;
    bo[tid] = f2bf(o0); bo[tid+256] = f2bf(o1); bo[tid+512] = f2bf(o2);
  }
}

// ---------------------------------------------------------------- GEMM 128x128 tile, BK=32, mfma 16x16x32 bf16
// W is PRE-TRANSPOSED: [N][K] row-major -> both A and B tiles stage linearly
// via global_load_lds (no VALU packing, no explicit ds_write).
template<int EPI>
__global__ __launch_bounds__(256) void gemm_k(
    const u16* __restrict__ A, const u16* __restrict__ W, const u16* __restrict__ bias,
    int N, int K,
    u16* __restrict__ qo, u16* __restrict__ ko, u16* __restrict__ vto,
    float* __restrict__ hres, u16* __restrict__ uo)
{
  __shared__ alignas(16) u16 Alds[128*32];
  __shared__ alignas(16) u16 Blds[128*32];
  int tid = threadIdx.x;
  int bn = blockIdx.x*128, bm = blockIdx.y*128;
  int lane = tid & 63, wv = tid >> 6;
  int l15 = lane & 15, quad = lane >> 4;
  int wm = (wv & 1)*64, wn = (wv >> 1)*64;
  f32x4 acc[4][4];
  #pragma unroll
  for (int i=0;i<4;i++)
    #pragma unroll
    for (int j=0;j<4;j++)
      acc[i][j] = (f32x4){0.f,0.f,0.f,0.f};

  for (int k0 = 0; k0 < K; k0 += 32){
    #pragma unroll
    for (int i=0;i<2;i++){
      int idx = tid + 256*i;
      int m = idx >> 2, oct = idx & 3;
      gl_lds16(A + (size_t)(bm+m)*K + k0 + oct*8, &Alds[idx*8]);
      gl_lds16(W + (size_t)(bn+m)*K + k0 + oct*8, &Blds[idx*8]);
    }
    __syncthreads();
    bf16x8 af[4], bfr[4];
    #pragma unroll
    for (int fm=0;fm<4;fm++) af[fm]  = *(const bf16x8*)&Alds[(wm + fm*16 + l15)*32 + quad*8];
    #pragma unroll
    for (int fn=0;fn<4;fn++) bfr[fn] = *(const bf16x8*)&Blds[(wn + fn*16 + l15)*32 + quad*8];
    #pragma unroll
    for (int fm=0;fm<4;fm++)
      #pragma unroll
      for (int fn=0;fn<4;fn++)
        acc[fm][fn] = __builtin_amdgcn_mfma_f32_16x16x32_bf16(af[fm], bfr[fn], acc[fm][fn], 0,0,0);
    __syncthreads();
  }

  // ---- epilogue: C row = bm+wm+fm*16+quad*4+r, col = bn+wn+fn*16+l15
  #pragma unroll
  for (int fn=0;fn<4;fn++){
    int col = bn + wn + fn*16 + l15;
    float bv = bf2f(bias[col]);
    int which=0, hh=0, hd=0;
    if (EPI==0){ which = col/768; int rem = col - which*768; hh = rem>>6; hd = rem&63; }
    #pragma unroll
    for (int fm=0;fm<4;fm++){
      int row0 = bm + wm + fm*16 + quad*4;
      #pragma unroll
      for (int r=0;r<4;r++){
        int row = row0 + r;
        float val = acc[fm][fn][r] + bv;
        if (EPI==0){
          int b = row / T_; int t = row - b*T_;
          int bh = b*NH_ + hh;
          u16 ob = f2bf(val);
          if (which==0)      qo[((size_t)bh*T_ + t)*HD_ + hd] = ob;
          else if (which==1) ko[((size_t)bh*T_ + t)*HD_ + hd] = ob;
          else               vto[((size_t)bh*HD_ + hd)*T_ + t] = ob;
        } else if (EPI==1){
          hres[(size_t)row*D_ + col] += val;
        } else {
          float xx = val;
          float g = 0.5f*xx*(1.0f + tanhf(0.7978845608028654f*(xx + 0.044715f*xx*xx*xx)));
          uo[(size_t)row*F_ + col] = f2bf(g);
        }
      }
    }
  }
}

// ---------------------------------------------------------------- rule mask helpers
__device__ __forceinline__ void tok_meta(int t, int& g, int& ts){
  if (t < P_){ g = 0; ts = -1; }
  else { int u = t - P_; ts = u / TPS_; int r = u - ts*TPS_; g = (r < NO_) ? 1 : 2; }
}

// ---------------------------------------------------------------- flash attention: 1 wave, 32 q-rows, 32-key tiles
// QK^T computed operand-SWAPPED: S^T = mfma(K_frag, Q_frag) -> col = q (lane&15),
// row = key (quad*4+reg). Softmax per q-row is lane-local over 8 regs + 2 shfl_xor
// (cross-quad) instead of 8 serial 4-step shfl chains. Single wave: no barriers.
#define MASKVAL (-30000.0f)
__global__ __launch_bounds__(64) void attn_k(const u16* __restrict__ q, const u16* __restrict__ kk_,
                                             const u16* __restrict__ vt, u16* __restrict__ att){
  __shared__ alignas(16) u16 Plds[2][16*40];
  int lane = threadIdx.x;
  int l15 = lane & 15, quad = lane >> 4;
  int bh = blockIdx.y;
  int b = bh / NH_, h = bh - b*NH_;
  // reversed dispatch: longest (largest qbase) blocks first -> less tail imbalance
  int qbase = ((int)gridDim.x - 1 - (int)blockIdx.x) * 32;
  const u16* Qb = q   + (size_t)bh*T_*HD_;
  const u16* Kb = kk_ + (size_t)bh*T_*HD_;
  const u16* Vb = vt  + (size_t)bh*HD_*T_;

  bf16x8 qa[2][2];
  #pragma unroll
  for (int mi=0;mi<2;mi++)
    #pragma unroll
    for (int c=0;c<2;c++)
      qa[mi][c] = *(const bf16x8*)(Qb + (size_t)(qbase + mi*16 + l15)*HD_ + c*32 + quad*8);

  f32x4 o[2][4];
  #pragma unroll
  for (int mi=0;mi<2;mi++)
    #pragma unroll
    for (int fn=0;fn<4;fn++) o[mi][fn] = (f32x4){0.f,0.f,0.f,0.f};

  // per-mi softmax state, lane-local at q = qbase + mi*16 + l15
  float m_[2] = {MASKVAL, MASKVAL};
  float l_[2] = {0.f, 0.f};
  int kmaxq[2]; int aE[2];
  #pragma unroll
  for (int mi=0;mi<2;mi++){
    int qg, qts; tok_meta(qbase + mi*16 + l15, qg, qts);
    kmaxq[mi] = (qg==0) ? P_ : P_ + TPS_*(qts+1);
    aE[mi] = (qg==2) ? 1 : 0;
  }

  int ts_max = (qbase + 31 - P_) / TPS_;
  int kend = (P_ + (ts_max+1)*TPS_ + 31) / 32;
  int rb = -P_;  // (kbase - P) mod TPS, in [-16,135]

  for (int kt = 0; kt < kend; kt++){
    int kbase = kt*32;
    bf16x8 kb[2][2];
    #pragma unroll
    for (int hf=0;hf<2;hf++)
      #pragma unroll
      for (int c=0;c<2;c++)
        kb[hf][c] = *(const bf16x8*)(Kb + (size_t)(kbase + hf*16 + l15)*HD_ + c*32 + quad*8);

    // S^T[key][q]: key = kbase + hf*16 + quad*4 + r, q = qbase + mi*16 + l15
    f32x4 sacc[2][2];
    #pragma unroll
    for (int mi=0;mi<2;mi++)
      #pragma unroll
      for (int hf=0;hf<2;hf++){
        f32x4 z = (f32x4){0.f,0.f,0.f,0.f};
        z = __builtin_amdgcn_mfma_f32_16x16x32_bf16(kb[hf][0], qa[mi][0], z, 0,0,0);
        z = __builtin_amdgcn_mfma_f32_16x16x32_bf16(kb[hf][1], qa[mi][1], z, 0,0,0);
        sacc[mi][hf] = z;
      }

    // mask + scale (division-free incremental key meta)
    float sc[2][8];
    #pragma unroll
    for (int hf=0;hf<2;hf++)
      #pragma unroll
      for (int r=0;r<4;r++){
        int off = hf*16 + quad*4 + r;
        int rrf = rb + off; rrf -= (rrf >= TPS_) ? TPS_ : 0;
        int pA = rrf < 0;            // prefix key
        int pB = rrf < NO_;          // obs (vs readout) key
        int k  = kbase + off;
        #pragma unroll
        for (int mi=0;mi<2;mi++){
          int ok = pA | ((k < kmaxq[mi]) & (aE[mi] | pB));
          sc[mi][hf*4+r] = ok ? sacc[mi][hf][r]*0.125f : MASKVAL;
        }
      }

    #pragma unroll
    for (int mi=0;mi<2;mi++){
      float mx = sc[mi][0];
      #pragma unroll
      for (int j=1;j<8;j++) mx = fmaxf(mx, sc[mi][j]);
      mx = fmaxf(mx, __shfl_xor(mx, 16, 64));
      mx = fmaxf(mx, __shfl_xor(mx, 32, 64));
      float mnew = fmaxf(m_[mi], mx);
      float pp[8];
      float rs = 0.f;
      #pragma unroll
      for (int j=0;j<8;j++){ pp[j] = __expf(sc[mi][j] - mnew); rs += pp[j]; }
      rs += __shfl_xor(rs, 16, 64);
      rs += __shfl_xor(rs, 32, 64);
      float alpha = __expf(m_[mi] - mnew);
      l_[mi] = l_[mi]*alpha + rs;
      m_[mi] = mnew;
      // broadcast alpha from lane (q = quad*4+r) to o-layout
      f32x4 av;
      #pragma unroll
      for (int r=0;r<4;r++) av[r] = __shfl(alpha, quad*4 + r, 16);
      #pragma unroll
      for (int fn=0;fn<4;fn++) o[mi][fn] *= av;
      // pack P -> Plds[q][key] (row l15, keys quad*4+r per hf)
      u32* wp0 = (u32*)&Plds[mi][l15*40 + quad*4];
      wp0[0] = pkbf(pp[0], pp[1]); wp0[1] = pkbf(pp[2], pp[3]);
      u32* wp1 = (u32*)&Plds[mi][l15*40 + 16 + quad*4];
      wp1[0] = pkbf(pp[4], pp[5]); wp1[1] = pkbf(pp[6], pp[7]);
    }

    bf16x8 pa[2];
    #pragma unroll
    for (int mi=0;mi<2;mi++) pa[mi] = *(const bf16x8*)&Plds[mi][l15*40 + quad*8];
    #pragma unroll
    for (int fn=0;fn<4;fn++){
      bf16x8 vb = *(const bf16x8*)(Vb + (size_t)(fn*16 + l15)*T_ + kbase + quad*8);
      #pragma unroll
      for (int mi=0;mi<2;mi++)
        o[mi][fn] = __builtin_amdgcn_mfma_f32_16x16x32_bf16(pa[mi], vb, o[mi][fn], 0,0,0);
    }
    rb += 32; rb -= (rb >= TPS_) ? TPS_ : 0;
  }

  #pragma unroll
  for (int mi=0;mi<2;mi++){
    float li = 1.0f / fmaxf(l_[mi], 1e-30f);
    f32x4 lv;
    #pragma unroll
    for (int r=0;r<4;r++) lv[r] = __shfl(li, quad*4 + r, 16);
    #pragma unroll
    for (int fn=0;fn<4;fn++){
      int d = fn*16 + l15;
      #pragma unroll
      for (int r=0;r<4;r++){
        int row = qbase + mi*16 + quad*4 + r;
        att[((size_t)b*T_ + row)*D_ + h*HD_ + d] = f2bf(o[mi][fn][r] * lv[r]);
      }
    }
  }
}

// ---------------------------------------------------------------- launch
extern "C" void kernel_launch(void* const* d_in, const int* in_sizes, int n_in,
                              void* d_out, int out_size, void* d_ws, size_t ws_size,
                              hipStream_t stream){
  char* p = (char*)d_ws;
  int* flag = (int*)p; p += 256;
  u16* c_pre  = (u16*)p; p += (size_t)98304*2;
  u16* c_obs  = (u16*)p; p += (size_t)7864320*2;
  u16* c_ro   = (u16*)p; p += (size_t)491520*2;
  u16* c_ln1s = (u16*)p; p += (size_t)9216*2;
  u16* c_ln1b = (u16*)p; p += (size_t)9216*2;
  u16* c_wqkv = (u16*)p; p += (size_t)21233664*2;
  u16* c_bqkv = (u16*)p; p += (size_t)27648*2;
  u16* c_wo   = (u16*)p; p += (size_t)7077888*2;
  u16* c_bo   = (u16*)p; p += (size_t)9216*2;
  u16* c_ln2s = (u16*)p; p += (size_t)9216*2;
  u16* c_ln2b = (u16*)p; p += (size_t)9216*2;
  u16* c_w1   = (u16*)p; p += (size_t)28311552*2;
  u16* c_b1   = (u16*)p; p += (size_t)36864*2;
  u16* c_w2   = (u16*)p; p += (size_t)28311552*2;
  u16* c_b2   = (u16*)p; p += (size_t)9216*2;
  u16* c_lnfs = (u16*)p; p += (size_t)768*2;
  u16* c_lnfb = (u16*)p; p += (size_t)768*2;
  float* h = (float*)p; p += (size_t)BT_*D_*4;
  u16* y   = (u16*)p;   p += (size_t)BT_*D_*2;
  u16* qb  = (u16*)p;   p += (size_t)BT_*D_*2;
  u16* kb  = (u16*)p;   p += (size_t)BT_*D_*2;
  u16* vtb = (u16*)p;   p += (size_t)BT_*D_*2;
  u16* ub  = (u16*)p;   p += (size_t)BT_*F_*2;
  u16* att = y;  // attn output reuses y (y dead after QKV gemm, rewritten by ln2)

  detect_k<<<1, 256, 0, stream>>>((const u16*)d_in[8], flag);

  auto cv = [&](const void* s, u16* d, int n){
    int g = (n + 2047) / 2048;
    conv_k<<<g, 256, 0, stream>>>(s, d, n, flag);
  };
  cv(d_in[0],  c_pre,  98304);
  cv(d_in[2],  c_obs,  7864320);
  cv(d_in[4],  c_ro,   491520);
  cv(d_in[6],  c_ln1s, 9216);
  cv(d_in[7],  c_ln1b, 9216);
  cv(d_in[9],  c_bqkv, 27648);
  cv(d_in[11], c_bo,   9216);
  cv(d_in[12], c_ln2s, 9216);
  cv(d_in[13], c_ln2b, 9216);
  cv(d_in[15], c_b1,   36864);
  cv(d_in[17], c_b2,   9216);
  cv(d_in[18], c_lnfs, 768);
  cv(d_in[19], c_lnfb, 768);
  auto cvT = [&](const void* s, u16* d, int Kd, int Nd){
    convT_k<<<dim3(Nd/32, Kd/32, L_), 256, 0, stream>>>(s, d, Kd, Nd, flag);
  };
  cvT(d_in[8],  c_wqkv, D_, 3*D_);
  cvT(d_in[10], c_wo,   D_, D_);
  cvT(d_in[14], c_w1,   D_, F_);
  cvT(d_in[16], c_w2,   F_, D_);

  init_h<<<BT_, 256, 0, stream>>>(c_pre, c_obs, c_ro, h);
  for (int l = 0; l < L_; l++){
    ln_k<<<BT_, 256, 0, stream>>>(h, c_ln1s + l*D_, c_ln1b + l*D_, y);
    gemm_k<0><<<dim3(18,86), 256, 0, stream>>>(y, c_wqkv + (size_t)l*D_*3*D_, c_bqkv + (size_t)l*3*D_,
                                               3*D_, D_, qb, kb, vtb, nullptr, nullptr);
    attn_k<<<dim3(43,96), 64, 0, stream>>>(qb, kb, vtb, att);
    gemm_k<1><<<dim3(6,86), 256, 0, stream>>>(att, c_wo + (size_t)l*D_*D_, c_bo + (size_t)l*D_,
                                              D_, D_, nullptr, nullptr, nullptr, h, nullptr);
    ln_k<<<BT_, 256, 0, stream>>>(h, c_ln2s + l*D_, c_ln2b + l*D_, y);
    gemm_k<2><<<dim3(24,86), 256, 0, stream>>>(y, c_w1 + (size_t)l*D_*F_, c_b1 + (size_t)l*F_,
                                               F_, D_, nullptr, nullptr, nullptr, nullptr, ub);
    gemm_k<1><<<dim3(6,86), 256, 0, stream>>>(ub, c_w2 + (size_t)l*F_*D_, c_b2 + (size_t)l*D_,
                                              D_, F_, nullptr, nullptr, nullptr, h, nullptr);
  }
  ln_out_k<<<BT_, 256, 0, stream>>>(h, c_lnfs, c_lnfb, d_out, flag);
}

// Round 3
// 6849.640 us; speedup vs baseline: 1.2931x; 1.0579x over previous
//
#include <hip/hip_runtime.h>

typedef unsigned short u16;
typedef unsigned int u32;
typedef __bf16 bf16x8 __attribute__((ext_vector_type(8)));
typedef float f32x4 __attribute__((ext_vector_type(4)));

#define B_ 8
#define HOR_ 10
#define P_ 16
#define NO_ 128
#define NR_ 8
#define TPS_ 136
#define T_ 1376
#define D_ 768
#define NH_ 12
#define HD_ 64
#define F_ 3072
#define L_ 12
#define BT_ (B_*T_)   /* 11008 */

__device__ __forceinline__ float bf2f(u16 u){ return __uint_as_float(((u32)u)<<16); }
__device__ __forceinline__ u16 f2bf(float f){
  u32 x = __float_as_uint(f);
  u32 r = (x + 0x7fffu + ((x>>16)&1u)) >> 16;
  return (u16)r;
}
__device__ __forceinline__ u32 pkbf(float a, float b){
  union { __bf16 h[2]; u32 w; } u;
  u.h[0] = (__bf16)a; u.h[1] = (__bf16)b;
  return u.w;
}

// async global->LDS, 16B per lane
__device__ __forceinline__ void gl_lds16(const u16* g, u16* l){
  __builtin_amdgcn_global_load_lds((const __attribute__((address_space(1))) void*)g,
                                   (__attribute__((address_space(3))) void*)l,
                                   16, 0, 0);
}

// bijective XCD-chunk swizzle (m204): consecutive work-ids land on the SAME XCD
__device__ __forceinline__ int xcd_swz(int lid, int nwg){
  int xcd = lid & 7, local = lid >> 3;
  int q = nwg >> 3, r = nwg & 7;
  int base = (xcd < r) ? xcd*(q+1) : r*(q+1) + (xcd-r)*q;
  return base + local;
}

// ---------------------------------------------------------------- dtype probe
// flag=1 -> inputs are fp32; flag=0 -> inputs are bf16.
__global__ __launch_bounds__(256) void detect_k(const u16* __restrict__ w, int* __restrict__ flag){
  int tid = threadIdx.x;
  int bad = 0;
  for (int i = tid; i < 8192; i += 256){
    int e = (w[i] >> 7) & 0xFF;
    bad += (e >= 0xF0);
  }
  #pragma unroll
  for (int m=1;m<64;m<<=1) bad += __shfl_xor(bad, m, 64);
  __shared__ int s[4];
  if ((tid & 63) == 0) s[tid>>6] = bad;
  __syncthreads();
  if (tid == 0) flag[0] = (s[0]+s[1]+s[2]+s[3] > 4) ? 1 : 0;
}

// ---------------------------------------------------------------- canonicalize any float tensor -> bf16
__global__ __launch_bounds__(256) void conv_k(const void* __restrict__ src, u16* __restrict__ dst,
                                              int n, const int* __restrict__ flag){
  int f = flag[0];
  int stride = gridDim.x * 256;
  int i0 = blockIdx.x*256 + threadIdx.x;
  if (f){
    const float* s = (const float*)src;
    for (int i = i0; i < n; i += stride) dst[i] = f2bf(s[i]);
  } else {
    const u16* s = (const u16*)src;
    for (int i = i0; i < n; i += stride) dst[i] = s[i];
  }
}

// ---------------------------------------------------------------- convert + transpose weights [L][K][N] -> bf16 [L][N][K]
__global__ __launch_bounds__(256) void convT_k(const void* __restrict__ src, u16* __restrict__ dst,
                                               int K, int N, const int* __restrict__ flag){
  __shared__ u16 t[32][33];
  int f = flag[0];
  size_t so = (size_t)blockIdx.z * K * N;
  size_t dz = (size_t)blockIdx.z * N * K;
  int k0 = blockIdx.y*32, n0 = blockIdx.x*32;
  int tid = threadIdx.x;
  int tx = tid & 31, ty = tid >> 5;   // ty in [0,8)
  #pragma unroll
  for (int r=0;r<32;r+=8){
    int k = k0 + ty + r, n = n0 + tx;
    u16 bv;
    if (f) bv = f2bf(((const float*)src)[so + (size_t)k*N + n]);
    else   bv = ((const u16*)src)[so + (size_t)k*N + n];
    t[ty+r][tx] = bv;
  }
  __syncthreads();
  #pragma unroll
  for (int r=0;r<32;r+=8){
    int n = n0 + ty + r, k = k0 + tx;
    dst[dz + (size_t)n*K + k] = t[tx][ty+r];
  }
}

// ---------------------------------------------------------------- init h (fp32 residual) from canonical bf16 tokens
__global__ __launch_bounds__(256) void init_h(const u16* __restrict__ pre, const u16* __restrict__ obs,
                                              const u16* __restrict__ ro, float* __restrict__ h){
  int bt = blockIdx.x; int b = bt / T_; int t = bt - b*T_;
  const u16* src;
  if (t < P_) src = pre + ((size_t)(b*P_ + t))*D_;
  else {
    int u = t - P_; int ts = u / TPS_; int r = u - ts*TPS_;
    if (r < NO_) src = obs + ((size_t)((b*HOR_ + ts)*NO_ + r))*D_;
    else         src = ro  + ((size_t)((b*HOR_ + ts)*NR_ + (r - NO_)))*D_;
  }
  float* dst = h + (size_t)bt*D_;
  for (int d = threadIdx.x; d < D_; d += 256) dst[d] = bf2f(src[d]);
}

// ---------------------------------------------------------------- LayerNorm: fp32 h -> bf16 y
__global__ __launch_bounds__(256) void ln_k(const float* __restrict__ h, const u16* __restrict__ s,
                                            const u16* __restrict__ bia, u16* __restrict__ y){
  int row = blockIdx.x;
  const float* x = h + (size_t)row*D_;
  int tid = threadIdx.x;
  float v0 = x[tid], v1 = x[tid+256], v2 = x[tid+512];
  float sum = v0+v1+v2;
  float sq  = v0*v0+v1*v1+v2*v2;
  #pragma unroll
  for (int m=1;m<64;m<<=1){ sum += __shfl_xor(sum,m,64); sq += __shfl_xor(sq,m,64); }
  __shared__ float ls[4], lq[4];
  int w = tid>>6;
  if ((tid&63)==0){ ls[w]=sum; lq[w]=sq; }
  __syncthreads();
  sum = ls[0]+ls[1]+ls[2]+ls[3];
  sq  = lq[0]+lq[1]+lq[2]+lq[3];
  float mu  = sum * (1.0f/D_);
  float var = sq * (1.0f/D_) - mu*mu;
  float rstd = rsqrtf(fmaxf(var, 0.f) + 1e-6f);
  u16* yo = y + (size_t)row*D_;
  yo[tid]     = f2bf((v0-mu)*rstd*bf2f(s[tid])     + bf2f(bia[tid]));
  yo[tid+256] = f2bf((v1-mu)*rstd*bf2f(s[tid+256]) + bf2f(bia[tid+256]));
  yo[tid+512] = f2bf((v2-mu)*rstd*bf2f(s[tid+512]) + bf2f(bia[tid+512]));
}

// ---------------------------------------------------------------- final LayerNorm: dual-dtype output
__global__ __launch_bounds__(256) void ln_out_k(const float* __restrict__ h, const u16* __restrict__ s,
                                                const u16* __restrict__ bia, void* __restrict__ out,
                                                const int* __restrict__ flag){
  int row = blockIdx.x;
  const float* x = h + (size_t)row*D_;
  int tid = threadIdx.x;
  float v0 = x[tid], v1 = x[tid+256], v2 = x[tid+512];
  float sum = v0+v1+v2;
  float sq  = v0*v0+v1*v1+v2*v2;
  #pragma unroll
  for (int m=1;m<64;m<<=1){ sum += __shfl_xor(sum,m,64); sq += __shfl_xor(sq,m,64); }
  __shared__ float ls[4], lq[4];
  int w = tid>>6;
  if ((tid&63)==0){ ls[w]=sum; lq[w]=sq; }
  __syncthreads();
  sum = ls[0]+ls[1]+ls[2]+ls[3];
  sq  = lq[0]+lq[1]+lq[2]+lq[3];
  float mu  = sum * (1.0f/D_);
  float var = sq * (1.0f/D_) - mu*mu;
  float rstd = rsqrtf(fmaxf(var, 0.f) + 1e-6f);
  float o0 = (v0-mu)*rstd*bf2f(s[tid])     + bf2f(bia[tid]);
  float o1 = (v1-mu)*rstd*bf2f(s[tid+256]) + bf2f(bia[tid+256]);
  float o2 = (v2-mu)*rstd*bf2f(s[tid+512]) + bf2f(bia[tid+512]);
  if (flag[0]){
    float* fo = (float*)out + (size_t)row*D_;
    fo[tid] = o0; fo[tid+256] = o1; fo[tid+512] = o2;
  } else {
    u16* bo = (u16*)out + (size_t)row*D_;
    bo[tid] = f2bf(o0); bo[tid+256] = f2bf(o1); bo[tid+512] = f2bf(o2);
  }
}

// ---------------------------------------------------------------- GEMM 128x128 tile, BK=32, mfma 16x16x32 bf16
// W pre-transposed [N][K]. Double-buffered LDS (T3 2-phase): stage tile t+1
// BEFORE compute of tile t -> HBM latency overlaps MFMA; one barrier per step.
// XCD-chunked block swizzle (T1/m204): each XCD owns a contiguous bm-band.
template<int EPI>
__global__ __launch_bounds__(256) void gemm_k(
    const u16* __restrict__ A, const u16* __restrict__ W, const u16* __restrict__ bias,
    int N, int K,
    u16* __restrict__ qo, u16* __restrict__ ko, u16* __restrict__ vto,
    float* __restrict__ hres, u16* __restrict__ uo)
{
  __shared__ alignas(16) u16 Alds[2][128*32];
  __shared__ alignas(16) u16 Blds[2][128*32];
  int tid = threadIdx.x;
  int nwg = gridDim.x * gridDim.y;
  int lid = blockIdx.x + blockIdx.y*gridDim.x;
  int swz = xcd_swz(lid, nwg);
  int bn = (swz % gridDim.x)*128, bm = (swz / gridDim.x)*128;
  int lane = tid & 63, wv = tid >> 6;
  int l15 = lane & 15, quad = lane >> 4;
  int wm = (wv & 1)*64, wn = (wv >> 1)*64;
  f32x4 acc[4][4];
  #pragma unroll
  for (int i=0;i<4;i++)
    #pragma unroll
    for (int j=0;j<4;j++)
      acc[i][j] = (f32x4){0.f,0.f,0.f,0.f};

  // per-thread staging addresses (two 16B chunks each for A and B)
  int m0 = tid >> 2, oct0 = tid & 3;           // idx = tid
  int m1 = (tid+256) >> 2, oct1 = tid & 3;     // idx = tid+256
  const u16* a0 = A + (size_t)(bm+m0)*K + oct0*8;
  const u16* a1 = A + (size_t)(bm+m1)*K + oct1*8;
  const u16* w0 = W + (size_t)(bn+m0)*K + oct0*8;
  const u16* w1 = W + (size_t)(bn+m1)*K + oct1*8;
  int s0 = tid*8, s1 = (tid+256)*8;

  int nt = K >> 5;
  // prologue: stage tile 0 into buf 0
  gl_lds16(a0, &Alds[0][s0]); gl_lds16(a1, &Alds[0][s1]);
  gl_lds16(w0, &Blds[0][s0]); gl_lds16(w1, &Blds[0][s1]);
  __syncthreads();

  int cur = 0;
  for (int t = 0; t < nt; t++){
    int k1 = (t+1) << 5;
    if (t+1 < nt){
      gl_lds16(a0 + k1, &Alds[cur^1][s0]); gl_lds16(a1 + k1, &Alds[cur^1][s1]);
      gl_lds16(w0 + k1, &Blds[cur^1][s0]); gl_lds16(w1 + k1, &Blds[cur^1][s1]);
    }
    bf16x8 af[4], bfr[4];
    #pragma unroll
    for (int fm=0;fm<4;fm++) af[fm]  = *(const bf16x8*)&Alds[cur][(wm + fm*16 + l15)*32 + quad*8];
    #pragma unroll
    for (int fn=0;fn<4;fn++) bfr[fn] = *(const bf16x8*)&Blds[cur][(wn + fn*16 + l15)*32 + quad*8];
    #pragma unroll
    for (int fm=0;fm<4;fm++)
      #pragma unroll
      for (int fn=0;fn<4;fn++)
        acc[fm][fn] = __builtin_amdgcn_mfma_f32_16x16x32_bf16(af[fm], bfr[fn], acc[fm][fn], 0,0,0);
    __syncthreads();   // drains vmcnt(0): tile t+1 staged; all reads of buf[cur] done
    cur ^= 1;
  }

  // ---- epilogue: C row = bm+wm+fm*16+quad*4+r, col = bn+wn+fn*16+l15
  #pragma unroll
  for (int fn=0;fn<4;fn++){
    int col = bn + wn + fn*16 + l15;
    float bv = bf2f(bias[col]);
    int which=0, hh=0, hd=0;
    if (EPI==0){ which = col/768; int rem = col - which*768; hh = rem>>6; hd = rem&63; }
    #pragma unroll
    for (int fm=0;fm<4;fm++){
      int row0 = bm + wm + fm*16 + quad*4;
      #pragma unroll
      for (int r=0;r<4;r++){
        int row = row0 + r;
        float val = acc[fm][fn][r] + bv;
        if (EPI==0){
          int b = row / T_; int t = row - b*T_;
          int bh = b*NH_ + hh;
          u16 ob = f2bf(val);
          if (which==0)      qo[((size_t)bh*T_ + t)*HD_ + hd] = ob;
          else if (which==1) ko[((size_t)bh*T_ + t)*HD_ + hd] = ob;
          else               vto[((size_t)bh*HD_ + hd)*T_ + t] = ob;
        } else if (EPI==1){
          hres[(size_t)row*D_ + col] += val;
        } else {
          float xx = val;
          float g = 0.5f*xx*(1.0f + tanhf(0.7978845608028654f*(xx + 0.044715f*xx*xx*xx)));
          uo[(size_t)row*F_ + col] = f2bf(g);
        }
      }
    }
  }
}

// ---------------------------------------------------------------- rule mask helpers
__device__ __forceinline__ void tok_meta(int t, int& g, int& ts){
  if (t < P_){ g = 0; ts = -1; }
  else { int u = t - P_; ts = u / TPS_; int r = u - ts*TPS_; g = (r < NO_) ? 1 : 2; }
}

// ---------------------------------------------------------------- flash attention: 1 wave, 32 q-rows, 32-key tiles
// QK^T operand-swapped: softmax lane-local; single wave, no barriers.
#define MASKVAL (-30000.0f)
__global__ __launch_bounds__(64) void attn_k(const u16* __restrict__ q, const u16* __restrict__ kk_,
                                             const u16* __restrict__ vt, u16* __restrict__ att){
  __shared__ alignas(16) u16 Plds[2][16*40];
  int lane = threadIdx.x;
  int l15 = lane & 15, quad = lane >> 4;
  int bh = blockIdx.y;
  int b = bh / NH_, h = bh - b*NH_;
  int qbase = ((int)gridDim.x - 1 - (int)blockIdx.x) * 32;
  const u16* Qb = q   + (size_t)bh*T_*HD_;
  const u16* Kb = kk_ + (size_t)bh*T_*HD_;
  const u16* Vb = vt  + (size_t)bh*HD_*T_;

  bf16x8 qa[2][2];
  #pragma unroll
  for (int mi=0;mi<2;mi++)
    #pragma unroll
    for (int c=0;c<2;c++)
      qa[mi][c] = *(const bf16x8*)(Qb + (size_t)(qbase + mi*16 + l15)*HD_ + c*32 + quad*8);

  f32x4 o[2][4];
  #pragma unroll
  for (int mi=0;mi<2;mi++)
    #pragma unroll
    for (int fn=0;fn<4;fn++) o[mi][fn] = (f32x4){0.f,0.f,0.f,0.f};

  float m_[2] = {MASKVAL, MASKVAL};
  float l_[2] = {0.f, 0.f};
  int kmaxq[2]; int aE[2];
  #pragma unroll
  for (int mi=0;mi<2;mi++){
    int qg, qts; tok_meta(qbase + mi*16 + l15, qg, qts);
    kmaxq[mi] = (qg==0) ? P_ : P_ + TPS_*(qts+1);
    aE[mi] = (qg==2) ? 1 : 0;
  }

  int ts_max = (qbase + 31 - P_) / TPS_;
  int kend = (P_ + (ts_max+1)*TPS_ + 31) / 32;
  int rb = -P_;  // (kbase - P) mod TPS, in [-16,135]

  for (int kt = 0; kt < kend; kt++){
    int kbase = kt*32;
    bf16x8 kb[2][2];
    #pragma unroll
    for (int hf=0;hf<2;hf++)
      #pragma unroll
      for (int c=0;c<2;c++)
        kb[hf][c] = *(const bf16x8*)(Kb + (size_t)(kbase + hf*16 + l15)*HD_ + c*32 + quad*8);

    f32x4 sacc[2][2];
    #pragma unroll
    for (int mi=0;mi<2;mi++)
      #pragma unroll
      for (int hf=0;hf<2;hf++){
        f32x4 z = (f32x4){0.f,0.f,0.f,0.f};
        z = __builtin_amdgcn_mfma_f32_16x16x32_bf16(kb[hf][0], qa[mi][0], z, 0,0,0);
        z = __builtin_amdgcn_mfma_f32_16x16x32_bf16(kb[hf][1], qa[mi][1], z, 0,0,0);
        sacc[mi][hf] = z;
      }

    float sc[2][8];
    #pragma unroll
    for (int hf=0;hf<2;hf++)
      #pragma unroll
      for (int r=0;r<4;r++){
        int off = hf*16 + quad*4 + r;
        int rrf = rb + off; rrf -= (rrf >= TPS_) ? TPS_ : 0;
        int pA = rrf < 0;
        int pB = rrf < NO_;
        int k  = kbase + off;
        #pragma unroll
        for (int mi=0;mi<2;mi++){
          int ok = pA | ((k < kmaxq[mi]) & (aE[mi] | pB));
          sc[mi][hf*4+r] = ok ? sacc[mi][hf][r]*0.125f : MASKVAL;
        }
      }

    #pragma unroll
    for (int mi=0;mi<2;mi++){
      float mx = sc[mi][0];
      #pragma unroll
      for (int j=1;j<8;j++) mx = fmaxf(mx, sc[mi][j]);
      mx = fmaxf(mx, __shfl_xor(mx, 16, 64));
      mx = fmaxf(mx, __shfl_xor(mx, 32, 64));
      float mnew = fmaxf(m_[mi], mx);
      float pp[8];
      float rs = 0.f;
      #pragma unroll
      for (int j=0;j<8;j++){ pp[j] = __expf(sc[mi][j] - mnew); rs += pp[j]; }
      rs += __shfl_xor(rs, 16, 64);
      rs += __shfl_xor(rs, 32, 64);
      float alpha = __expf(m_[mi] - mnew);
      l_[mi] = l_[mi]*alpha + rs;
      m_[mi] = mnew;
      f32x4 av;
      #pragma unroll
      for (int r=0;r<4;r++) av[r] = __shfl(alpha, quad*4 + r, 16);
      #pragma unroll
      for (int fn=0;fn<4;fn++) o[mi][fn] *= av;
      u32* wp0 = (u32*)&Plds[mi][l15*40 + quad*4];
      wp0[0] = pkbf(pp[0], pp[1]); wp0[1] = pkbf(pp[2], pp[3]);
      u32* wp1 = (u32*)&Plds[mi][l15*40 + 16 + quad*4];
      wp1[0] = pkbf(pp[4], pp[5]); wp1[1] = pkbf(pp[6], pp[7]);
    }

    bf16x8 pa[2];
    #pragma unroll
    for (int mi=0;mi<2;mi++) pa[mi] = *(const bf16x8*)&Plds[mi][l15*40 + quad*8];
    #pragma unroll
    for (int fn=0;fn<4;fn++){
      bf16x8 vb = *(const bf16x8*)(Vb + (size_t)(fn*16 + l15)*T_ + kbase + quad*8);
      #pragma unroll
      for (int mi=0;mi<2;mi++)
        o[mi][fn] = __builtin_amdgcn_mfma_f32_16x16x32_bf16(pa[mi], vb, o[mi][fn], 0,0,0);
    }
    rb += 32; rb -= (rb >= TPS_) ? TPS_ : 0;
  }

  #pragma unroll
  for (int mi=0;mi<2;mi++){
    float li = 1.0f / fmaxf(l_[mi], 1e-30f);
    f32x4 lv;
    #pragma unroll
    for (int r=0;r<4;r++) lv[r] = __shfl(li, quad*4 + r, 16);
    #pragma unroll
    for (int fn=0;fn<4;fn++){
      int d = fn*16 + l15;
      #pragma unroll
      for (int r=0;r<4;r++){
        int row = qbase + mi*16 + quad*4 + r;
        att[((size_t)b*T_ + row)*D_ + h*HD_ + d] = f2bf(o[mi][fn][r] * lv[r]);
      }
    }
  }
}

// ---------------------------------------------------------------- launch
extern "C" void kernel_launch(void* const* d_in, const int* in_sizes, int n_in,
                              void* d_out, int out_size, void* d_ws, size_t ws_size,
                              hipStream_t stream){
  char* p = (char*)d_ws;
  int* flag = (int*)p; p += 256;
  u16* c_pre  = (u16*)p; p += (size_t)98304*2;
  u16* c_obs  = (u16*)p; p += (size_t)7864320*2;
  u16* c_ro   = (u16*)p; p += (size_t)491520*2;
  u16* c_ln1s = (u16*)p; p += (size_t)9216*2;
  u16* c_ln1b = (u16*)p; p += (size_t)9216*2;
  u16* c_wqkv = (u16*)p; p += (size_t)21233664*2;
  u16* c_bqkv = (u16*)p; p += (size_t)27648*2;
  u16* c_wo   = (u16*)p; p += (size_t)7077888*2;
  u16* c_bo   = (u16*)p; p += (size_t)9216*2;
  u16* c_ln2s = (u16*)p; p += (size_t)9216*2;
  u16* c_ln2b = (u16*)p; p += (size_t)9216*2;
  u16* c_w1   = (u16*)p; p += (size_t)28311552*2;
  u16* c_b1   = (u16*)p; p += (size_t)36864*2;
  u16* c_w2   = (u16*)p; p += (size_t)28311552*2;
  u16* c_b2   = (u16*)p; p += (size_t)9216*2;
  u16* c_lnfs = (u16*)p; p += (size_t)768*2;
  u16* c_lnfb = (u16*)p; p += (size_t)768*2;
  float* h = (float*)p; p += (size_t)BT_*D_*4;
  u16* y   = (u16*)p;   p += (size_t)BT_*D_*2;
  u16* qb  = (u16*)p;   p += (size_t)BT_*D_*2;
  u16* kb  = (u16*)p;   p += (size_t)BT_*D_*2;
  u16* vtb = (u16*)p;   p += (size_t)BT_*D_*2;
  u16* ub  = (u16*)p;   p += (size_t)BT_*F_*2;
  u16* att = y;  // attn output reuses y (y dead after QKV gemm, rewritten by ln2)

  detect_k<<<1, 256, 0, stream>>>((const u16*)d_in[8], flag);

  auto cv = [&](const void* s, u16* d, int n){
    int g = (n + 2047) / 2048;
    conv_k<<<g, 256, 0, stream>>>(s, d, n, flag);
  };
  cv(d_in[0],  c_pre,  98304);
  cv(d_in[2],  c_obs,  7864320);
  cv(d_in[4],  c_ro,   491520);
  cv(d_in[6],  c_ln1s, 9216);
  cv(d_in[7],  c_ln1b, 9216);
  cv(d_in[9],  c_bqkv, 27648);
  cv(d_in[11], c_bo,   9216);
  cv(d_in[12], c_ln2s, 9216);
  cv(d_in[13], c_ln2b, 9216);
  cv(d_in[15], c_b1,   36864);
  cv(d_in[17], c_b2,   9216);
  cv(d_in[18], c_lnfs, 768);
  cv(d_in[19], c_lnfb, 768);
  auto cvT = [&](const void* s, u16* d, int Kd, int Nd){
    convT_k<<<dim3(Nd/32, Kd/32, L_), 256, 0, stream>>>(s, d, Kd, Nd, flag);
  };
  cvT(d_in[8],  c_wqkv, D_, 3*D_);
  cvT(d_in[10], c_wo,   D_, D_);
  cvT(d_in[14], c_w1,   D_, F_);
  cvT(d_in[16], c_w2,   F_, D_);

  init_h<<<BT_, 256, 0, stream>>>(c_pre, c_obs, c_ro, h);
  for (int l = 0; l < L_; l++){
    ln_k<<<BT_, 256, 0, stream>>>(h, c_ln1s + l*D_, c_ln1b + l*D_, y);
    gemm_k<0><<<dim3(18,86), 256, 0, stream>>>(y, c_wqkv + (size_t)l*D_*3*D_, c_bqkv + (size_t)l*3*D_,
                                               3*D_, D_, qb, kb, vtb, nullptr, nullptr);
    attn_k<<<dim3(43,96), 64, 0, stream>>>(qb, kb, vtb, att);
    gemm_k<1><<<dim3(6,86), 256, 0, stream>>>(att, c_wo + (size_t)l*D_*D_, c_bo + (size_t)l*D_,
                                              D_, D_, nullptr, nullptr, nullptr, h, nullptr);
    ln_k<<<BT_, 256, 0, stream>>>(h, c_ln2s + l*D_, c_ln2b + l*D_, y);
    gemm_k<2><<<dim3(24,86), 256, 0, stream>>>(y, c_w1 + (size_t)l*D_*F_, c_b1 + (size_t)l*F_,
                                               F_, D_, nullptr, nullptr, nullptr, nullptr, ub);
    gemm_k<1><<<dim3(6,86), 256, 0, stream>>>(ub, c_w2 + (size_t)l*F_*D_, c_b2 + (size_t)l*D_,
                                              D_, F_, nullptr, nullptr, nullptr, h, nullptr);
  }
  ln_out_k<<<BT_, 256, 0, stream>>>(h, c_lnfs, c_lnfb, d_out, flag);
}

// Round 4
// 6655.087 us; speedup vs baseline: 1.3309x; 1.0292x over previous
//
#include <hip/hip_runtime.h>

typedef unsigned short u16;
typedef unsigned int u32;
typedef __bf16 bf16x8 __attribute__((ext_vector_type(8)));
typedef float f32x4 __attribute__((ext_vector_type(4)));

#define B_ 8
#define HOR_ 10
#define P_ 16
#define NO_ 128
#define NR_ 8
#define TPS_ 136
#define T_ 1376
#define D_ 768
#define NH_ 12
#define HD_ 64
#define F_ 3072
#define L_ 12
#define BT_ (B_*T_)   /* 11008 */

__device__ __forceinline__ float bf2f(u16 u){ return __uint_as_float(((u32)u)<<16); }
__device__ __forceinline__ u16 f2bf(float f){
  u32 x = __float_as_uint(f);
  u32 r = (x + 0x7fffu + ((x>>16)&1u)) >> 16;
  return (u16)r;
}
__device__ __forceinline__ u32 pkbf(float a, float b){
  union { __bf16 h[2]; u32 w; } u;
  u.h[0] = (__bf16)a; u.h[1] = (__bf16)b;
  return u.w;
}

// async global->LDS, 16B per lane
__device__ __forceinline__ void gl_lds16(const u16* g, u16* l){
  __builtin_amdgcn_global_load_lds((const __attribute__((address_space(1))) void*)g,
                                   (__attribute__((address_space(3))) void*)l,
                                   16, 0, 0);
}

// bijective XCD-chunk swizzle (m204): consecutive work-ids land on the SAME XCD
__device__ __forceinline__ int xcd_swz(int lid, int nwg){
  int xcd = lid & 7, local = lid >> 3;
  int q = nwg >> 3, r = nwg & 7;
  int base = (xcd < r) ? xcd*(q+1) : r*(q+1) + (xcd-r)*q;
  return base + local;
}

// ---------------------------------------------------------------- dtype probe
__global__ __launch_bounds__(256) void detect_k(const u16* __restrict__ w, int* __restrict__ flag){
  int tid = threadIdx.x;
  int bad = 0;
  for (int i = tid; i < 8192; i += 256){
    int e = (w[i] >> 7) & 0xFF;
    bad += (e >= 0xF0);
  }
  #pragma unroll
  for (int m=1;m<64;m<<=1) bad += __shfl_xor(bad, m, 64);
  __shared__ int s[4];
  if ((tid & 63) == 0) s[tid>>6] = bad;
  __syncthreads();
  if (tid == 0) flag[0] = (s[0]+s[1]+s[2]+s[3] > 4) ? 1 : 0;
}

// ---------------------------------------------------------------- canonicalize any float tensor -> bf16
__global__ __launch_bounds__(256) void conv_k(const void* __restrict__ src, u16* __restrict__ dst,
                                              int n, const int* __restrict__ flag){
  int f = flag[0];
  int stride = gridDim.x * 256;
  int i0 = blockIdx.x*256 + threadIdx.x;
  if (f){
    const float* s = (const float*)src;
    for (int i = i0; i < n; i += stride) dst[i] = f2bf(s[i]);
  } else {
    const u16* s = (const u16*)src;
    for (int i = i0; i < n; i += stride) dst[i] = s[i];
  }
}

// ---------------------------------------------------------------- convert + transpose weights [L][K][N] -> bf16 [L][N][K]
__global__ __launch_bounds__(256) void convT_k(const void* __restrict__ src, u16* __restrict__ dst,
                                               int K, int N, const int* __restrict__ flag){
  __shared__ u16 t[32][33];
  int f = flag[0];
  size_t so = (size_t)blockIdx.z * K * N;
  size_t dz = (size_t)blockIdx.z * N * K;
  int k0 = blockIdx.y*32, n0 = blockIdx.x*32;
  int tid = threadIdx.x;
  int tx = tid & 31, ty = tid >> 5;   // ty in [0,8)
  #pragma unroll
  for (int r=0;r<32;r+=8){
    int k = k0 + ty + r, n = n0 + tx;
    u16 bv;
    if (f) bv = f2bf(((const float*)src)[so + (size_t)k*N + n]);
    else   bv = ((const u16*)src)[so + (size_t)k*N + n];
    t[ty+r][tx] = bv;
  }
  __syncthreads();
  #pragma unroll
  for (int r=0;r<32;r+=8){
    int n = n0 + ty + r, k = k0 + tx;
    dst[dz + (size_t)n*K + k] = t[tx][ty+r];
  }
}

// ---------------------------------------------------------------- init h (fp32 residual) from canonical bf16 tokens
__global__ __launch_bounds__(256) void init_h(const u16* __restrict__ pre, const u16* __restrict__ obs,
                                              const u16* __restrict__ ro, float* __restrict__ h){
  int bt = blockIdx.x; int b = bt / T_; int t = bt - b*T_;
  const u16* src;
  if (t < P_) src = pre + ((size_t)(b*P_ + t))*D_;
  else {
    int u = t - P_; int ts = u / TPS_; int r = u - ts*TPS_;
    if (r < NO_) src = obs + ((size_t)((b*HOR_ + ts)*NO_ + r))*D_;
    else         src = ro  + ((size_t)((b*HOR_ + ts)*NR_ + (r - NO_)))*D_;
  }
  float* dst = h + (size_t)bt*D_;
  for (int d = threadIdx.x; d < D_; d += 256) dst[d] = bf2f(src[d]);
}

// ---------------------------------------------------------------- LayerNorm: fp32 h -> bf16 y
__global__ __launch_bounds__(256) void ln_k(const float* __restrict__ h, const u16* __restrict__ s,
                                            const u16* __restrict__ bia, u16* __restrict__ y){
  int row = blockIdx.x;
  const float* x = h + (size_t)row*D_;
  int tid = threadIdx.x;
  float v0 = x[tid], v1 = x[tid+256], v2 = x[tid+512];
  float sum = v0+v1+v2;
  float sq  = v0*v0+v1*v1+v2*v2;
  #pragma unroll
  for (int m=1;m<64;m<<=1){ sum += __shfl_xor(sum,m,64); sq += __shfl_xor(sq,m,64); }
  __shared__ float ls[4], lq[4];
  int w = tid>>6;
  if ((tid&63)==0){ ls[w]=sum; lq[w]=sq; }
  __syncthreads();
  sum = ls[0]+ls[1]+ls[2]+ls[3];
  sq  = lq[0]+lq[1]+lq[2]+lq[3];
  float mu  = sum * (1.0f/D_);
  float var = sq * (1.0f/D_) - mu*mu;
  float rstd = rsqrtf(fmaxf(var, 0.f) + 1e-6f);
  u16* yo = y + (size_t)row*D_;
  yo[tid]     = f2bf((v0-mu)*rstd*bf2f(s[tid])     + bf2f(bia[tid]));
  yo[tid+256] = f2bf((v1-mu)*rstd*bf2f(s[tid+256]) + bf2f(bia[tid+256]));
  yo[tid+512] = f2bf((v2-mu)*rstd*bf2f(s[tid+512]) + bf2f(bia[tid+512]));
}

// ---------------------------------------------------------------- final LayerNorm: dual-dtype output
__global__ __launch_bounds__(256) void ln_out_k(const float* __restrict__ h, const u16* __restrict__ s,
                                                const u16* __restrict__ bia, void* __restrict__ out,
                                                const int* __restrict__ flag){
  int row = blockIdx.x;
  const float* x = h + (size_t)row*D_;
  int tid = threadIdx.x;
  float v0 = x[tid], v1 = x[tid+256], v2 = x[tid+512];
  float sum = v0+v1+v2;
  float sq  = v0*v0+v1*v1+v2*v2;
  #pragma unroll
  for (int m=1;m<64;m<<=1){ sum += __shfl_xor(sum,m,64); sq += __shfl_xor(sq,m,64); }
  __shared__ float ls[4], lq[4];
  int w = tid>>6;
  if ((tid&63)==0){ ls[w]=sum; lq[w]=sq; }
  __syncthreads();
  sum = ls[0]+ls[1]+ls[2]+ls[3];
  sq  = lq[0]+lq[1]+lq[2]+lq[3];
  float mu  = sum * (1.0f/D_);
  float var = sq * (1.0f/D_) - mu*mu;
  float rstd = rsqrtf(fmaxf(var, 0.f) + 1e-6f);
  float o0 = (v0-mu)*rstd*bf2f(s[tid])     + bf2f(bia[tid]);
  float o1 = (v1-mu)*rstd*bf2f(s[tid+256]) + bf2f(bia[tid+256]);
  float o2 = (v2-mu)*rstd*bf2f(s[tid+512]) + bf2f(bia[tid+512]);
  if (flag[0]){
    float* fo = (float*)out + (size_t)row*D_;
    fo[tid] = o0; fo[tid+256] = o1; fo[tid+512] = o2;
  } else {
    u16* bo = (u16*)out + (size_t)row*D_;
    bo[tid] = f2bf(o0); bo[tid+256] = f2bf(o1); bo[tid+512] = f2bf(o2);
  }
}

// ---------------------------------------------------------------- GEMM 128x128 tile, BK=32, mfma 16x16x32 bf16
// W pre-transposed [N][K]. T3+T4: 3-buffer depth-2 pipeline with COUNTED vmcnt
// (never 0 in steady state) + raw s_barrier -- prefetched loads stay in flight
// across barriers. XCD-chunked block swizzle (T1/m204).
template<int EPI>
__global__ __launch_bounds__(256) void gemm_k(
    const u16* __restrict__ A, const u16* __restrict__ W, const u16* __restrict__ bias,
    int N, int K,
    u16* __restrict__ qo, u16* __restrict__ ko, u16* __restrict__ vto,
    float* __restrict__ hres, u16* __restrict__ uo)
{
  __shared__ alignas(16) u16 Alds[3][128*32];
  __shared__ alignas(16) u16 Blds[3][128*32];
  int tid = threadIdx.x;
  int nwg = gridDim.x * gridDim.y;
  int lid = blockIdx.x + blockIdx.y*gridDim.x;
  int swz = xcd_swz(lid, nwg);
  int bn = (swz % gridDim.x)*128, bm = (swz / gridDim.x)*128;
  int lane = tid & 63, wv = tid >> 6;
  int l15 = lane & 15, quad = lane >> 4;
  int wm = (wv & 1)*64, wn = (wv >> 1)*64;
  f32x4 acc[4][4];
  #pragma unroll
  for (int i=0;i<4;i++)
    #pragma unroll
    for (int j=0;j<4;j++)
      acc[i][j] = (f32x4){0.f,0.f,0.f,0.f};

  // per-thread staging addresses (two 16B chunks each for A and B)
  int m0 = tid >> 2, oct0 = tid & 3;
  int m1 = (tid+256) >> 2;
  const u16* a0 = A + (size_t)(bm+m0)*K + oct0*8;
  const u16* a1 = A + (size_t)(bm+m1)*K + oct0*8;
  const u16* w0 = W + (size_t)(bn+m0)*K + oct0*8;
  const u16* w1 = W + (size_t)(bn+m1)*K + oct0*8;
  int s0 = tid*8, s1 = (tid+256)*8;

  int nt = K >> 5;
  // prologue: stage tiles 0 and 1 (8 outstanding loads)
  gl_lds16(a0, &Alds[0][s0]); gl_lds16(a1, &Alds[0][s1]);
  gl_lds16(w0, &Blds[0][s0]); gl_lds16(w1, &Blds[0][s1]);
  if (nt > 1){
    gl_lds16(a0+32, &Alds[1][s0]); gl_lds16(a1+32, &Alds[1][s1]);
    gl_lds16(w0+32, &Blds[1][s0]); gl_lds16(w1+32, &Blds[1][s1]);
  }

  int nb = 0;  // buffer holding tile t
  for (int t = 0; t < nt; t++){
    if (t+2 < nt){
      int pb = nb + 2; pb -= (pb >= 3) ? 3 : 0;
      int k2 = (t+2) << 5;
      gl_lds16(a0 + k2, &Alds[pb][s0]); gl_lds16(a1 + k2, &Alds[pb][s1]);
      gl_lds16(w0 + k2, &Blds[pb][s0]); gl_lds16(w1 + k2, &Blds[pb][s1]);
      // 12 outstanding (tiles t,t+1,t+2): wait only for tile t's 4
      asm volatile("s_waitcnt vmcnt(8)" ::: "memory");
    } else if (t+1 < nt){
      asm volatile("s_waitcnt vmcnt(4)" ::: "memory");
    } else {
      asm volatile("s_waitcnt vmcnt(0)" ::: "memory");
    }
    __builtin_amdgcn_sched_barrier(0);
    __builtin_amdgcn_s_barrier();   // publish tile t (raw: prefetch stays in flight)

    bf16x8 af[4], bfr[4];
    #pragma unroll
    for (int fm=0;fm<4;fm++) af[fm]  = *(const bf16x8*)&Alds[nb][(wm + fm*16 + l15)*32 + quad*8];
    #pragma unroll
    for (int fn=0;fn<4;fn++) bfr[fn] = *(const bf16x8*)&Blds[nb][(wn + fn*16 + l15)*32 + quad*8];
    #pragma unroll
    for (int fm=0;fm<4;fm++)
      #pragma unroll
      for (int fn=0;fn<4;fn++)
        acc[fm][fn] = __builtin_amdgcn_mfma_f32_16x16x32_bf16(af[fm], bfr[fn], acc[fm][fn], 0,0,0);

    __builtin_amdgcn_sched_barrier(0);
    __builtin_amdgcn_s_barrier();   // all waves done reading buf[nb] -> reusable at t+1
    nb = (nb == 2) ? 0 : nb + 1;
  }

  // ---- epilogue: C row = bm+wm+fm*16+quad*4+r, col = bn+wn+fn*16+l15
  #pragma unroll
  for (int fn=0;fn<4;fn++){
    int col = bn + wn + fn*16 + l15;
    float bv = bf2f(bias[col]);
    int which=0, hh=0, hd=0;
    if (EPI==0){ which = col/768; int rem = col - which*768; hh = rem>>6; hd = rem&63; }
    #pragma unroll
    for (int fm=0;fm<4;fm++){
      int row0 = bm + wm + fm*16 + quad*4;
      #pragma unroll
      for (int r=0;r<4;r++){
        int row = row0 + r;
        float val = acc[fm][fn][r] + bv;
        if (EPI==0){
          int b = row / T_; int t = row - b*T_;
          int bh = b*NH_ + hh;
          u16 ob = f2bf(val);
          if (which==0)      qo[((size_t)bh*T_ + t)*HD_ + hd] = ob;
          else if (which==1) ko[((size_t)bh*T_ + t)*HD_ + hd] = ob;
          else               vto[((size_t)bh*HD_ + hd)*T_ + t] = ob;
        } else if (EPI==1){
          hres[(size_t)row*D_ + col] += val;
        } else {
          // gelu_tanh(x) = x * sigmoid(2*0.7978845608*(x + 0.044715 x^3))
          float xx = val;
          float u = 1.5957691216057308f*(xx + 0.044715f*xx*xx*xx);
          float g = xx * __builtin_amdgcn_rcpf(1.0f + __expf(-u));
          uo[(size_t)row*F_ + col] = f2bf(g);
        }
      }
    }
  }
}

// ---------------------------------------------------------------- rule mask helpers
__device__ __forceinline__ void tok_meta(int t, int& g, int& ts){
  if (t < P_){ g = 0; ts = -1; }
  else { int u = t - P_; ts = u / TPS_; int r = u - ts*TPS_; g = (r < NO_) ? 1 : 2; }
}

// ---------------------------------------------------------------- flash attention: 1 wave, 32 q-rows, 32-key tiles
// QK^T operand-swapped: softmax lane-local; single wave, no barriers.
#define MASKVAL (-30000.0f)
__global__ __launch_bounds__(64) void attn_k(const u16* __restrict__ q, const u16* __restrict__ kk_,
                                             const u16* __restrict__ vt, u16* __restrict__ att){
  __shared__ alignas(16) u16 Plds[2][16*40];
  int lane = threadIdx.x;
  int l15 = lane & 15, quad = lane >> 4;
  int bh = blockIdx.y;
  int b = bh / NH_, h = bh - b*NH_;
  int qbase = ((int)gridDim.x - 1 - (int)blockIdx.x) * 32;
  const u16* Qb = q   + (size_t)bh*T_*HD_;
  const u16* Kb = kk_ + (size_t)bh*T_*HD_;
  const u16* Vb = vt  + (size_t)bh*HD_*T_;

  bf16x8 qa[2][2];
  #pragma unroll
  for (int mi=0;mi<2;mi++)
    #pragma unroll
    for (int c=0;c<2;c++)
      qa[mi][c] = *(const bf16x8*)(Qb + (size_t)(qbase + mi*16 + l15)*HD_ + c*32 + quad*8);

  f32x4 o[2][4];
  #pragma unroll
  for (int mi=0;mi<2;mi++)
    #pragma unroll
    for (int fn=0;fn<4;fn++) o[mi][fn] = (f32x4){0.f,0.f,0.f,0.f};

  float m_[2] = {MASKVAL, MASKVAL};
  float l_[2] = {0.f, 0.f};
  int kmaxq[2]; int aE[2];
  #pragma unroll
  for (int mi=0;mi<2;mi++){
    int qg, qts; tok_meta(qbase + mi*16 + l15, qg, qts);
    kmaxq[mi] = (qg==0) ? P_ : P_ + TPS_*(qts+1);
    aE[mi] = (qg==2) ? 1 : 0;
  }

  int ts_max = (qbase + 31 - P_) / TPS_;
  int kend = (P_ + (ts_max+1)*TPS_ + 31) / 32;
  int rb = -P_;  // (kbase - P) mod TPS, in [-16,135]

  for (int kt = 0; kt < kend; kt++){
    int kbase = kt*32;
    bf16x8 kb[2][2];
    #pragma unroll
    for (int hf=0;hf<2;hf++)
      #pragma unroll
      for (int c=0;c<2;c++)
        kb[hf][c] = *(const bf16x8*)(Kb + (size_t)(kbase + hf*16 + l15)*HD_ + c*32 + quad*8);

    f32x4 sacc[2][2];
    #pragma unroll
    for (int mi=0;mi<2;mi++)
      #pragma unroll
      for (int hf=0;hf<2;hf++){
        f32x4 z = (f32x4){0.f,0.f,0.f,0.f};
        z = __builtin_amdgcn_mfma_f32_16x16x32_bf16(kb[hf][0], qa[mi][0], z, 0,0,0);
        z = __builtin_amdgcn_mfma_f32_16x16x32_bf16(kb[hf][1], qa[mi][1], z, 0,0,0);
        sacc[mi][hf] = z;
      }

    float sc[2][8];
    #pragma unroll
    for (int hf=0;hf<2;hf++)
      #pragma unroll
      for (int r=0;r<4;r++){
        int off = hf*16 + quad*4 + r;
        int rrf = rb + off; rrf -= (rrf >= TPS_) ? TPS_ : 0;
        int pA = rrf < 0;
        int pB = rrf < NO_;
        int k  = kbase + off;
        #pragma unroll
        for (int mi=0;mi<2;mi++){
          int ok = pA | ((k < kmaxq[mi]) & (aE[mi] | pB));
          sc[mi][hf*4+r] = ok ? sacc[mi][hf][r]*0.125f : MASKVAL;
        }
      }

    #pragma unroll
    for (int mi=0;mi<2;mi++){
      float mx = sc[mi][0];
      #pragma unroll
      for (int j=1;j<8;j++) mx = fmaxf(mx, sc[mi][j]);
      mx = fmaxf(mx, __shfl_xor(mx, 16, 64));
      mx = fmaxf(mx, __shfl_xor(mx, 32, 64));
      float mnew = fmaxf(m_[mi], mx);
      float pp[8];
      float rs = 0.f;
      #pragma unroll
      for (int j=0;j<8;j++){ pp[j] = __expf(sc[mi][j] - mnew); rs += pp[j]; }
      rs += __shfl_xor(rs, 16, 64);
      rs += __shfl_xor(rs, 32, 64);
      float alpha = __expf(m_[mi] - mnew);
      l_[mi] = l_[mi]*alpha + rs;
      m_[mi] = mnew;
      f32x4 av;
      #pragma unroll
      for (int r=0;r<4;r++) av[r] = __shfl(alpha, quad*4 + r, 16);
      #pragma unroll
      for (int fn=0;fn<4;fn++) o[mi][fn] *= av;
      u32* wp0 = (u32*)&Plds[mi][l15*40 + quad*4];
      wp0[0] = pkbf(pp[0], pp[1]); wp0[1] = pkbf(pp[2], pp[3]);
      u32* wp1 = (u32*)&Plds[mi][l15*40 + 16 + quad*4];
      wp1[0] = pkbf(pp[4], pp[5]); wp1[1] = pkbf(pp[6], pp[7]);
    }

    bf16x8 pa[2];
    #pragma unroll
    for (int mi=0;mi<2;mi++) pa[mi] = *(const bf16x8*)&Plds[mi][l15*40 + quad*8];
    #pragma unroll
    for (int fn=0;fn<4;fn++){
      bf16x8 vb = *(const bf16x8*)(Vb + (size_t)(fn*16 + l15)*T_ + kbase + quad*8);
      #pragma unroll
      for (int mi=0;mi<2;mi++)
        o[mi][fn] = __builtin_amdgcn_mfma_f32_16x16x32_bf16(pa[mi], vb, o[mi][fn], 0,0,0);
    }
    rb += 32; rb -= (rb >= TPS_) ? TPS_ : 0;
  }

  #pragma unroll
  for (int mi=0;mi<2;mi++){
    float li = 1.0f / fmaxf(l_[mi], 1e-30f);
    f32x4 lv;
    #pragma unroll
    for (int r=0;r<4;r++) lv[r] = __shfl(li, quad*4 + r, 16);
    #pragma unroll
    for (int fn=0;fn<4;fn++){
      int d = fn*16 + l15;
      #pragma unroll
      for (int r=0;r<4;r++){
        int row = qbase + mi*16 + quad*4 + r;
        att[((size_t)b*T_ + row)*D_ + h*HD_ + d] = f2bf(o[mi][fn][r] * lv[r]);
      }
    }
  }
}

// ---------------------------------------------------------------- launch
extern "C" void kernel_launch(void* const* d_in, const int* in_sizes, int n_in,
                              void* d_out, int out_size, void* d_ws, size_t ws_size,
                              hipStream_t stream){
  char* p = (char*)d_ws;
  int* flag = (int*)p; p += 256;
  u16* c_pre  = (u16*)p; p += (size_t)98304*2;
  u16* c_obs  = (u16*)p; p += (size_t)7864320*2;
  u16* c_ro   = (u16*)p; p += (size_t)491520*2;
  u16* c_ln1s = (u16*)p; p += (size_t)9216*2;
  u16* c_ln1b = (u16*)p; p += (size_t)9216*2;
  u16* c_wqkv = (u16*)p; p += (size_t)21233664*2;
  u16* c_bqkv = (u16*)p; p += (size_t)27648*2;
  u16* c_wo   = (u16*)p; p += (size_t)7077888*2;
  u16* c_bo   = (u16*)p; p += (size_t)9216*2;
  u16* c_ln2s = (u16*)p; p += (size_t)9216*2;
  u16* c_ln2b = (u16*)p; p += (size_t)9216*2;
  u16* c_w1   = (u16*)p; p += (size_t)28311552*2;
  u16* c_b1   = (u16*)p; p += (size_t)36864*2;
  u16* c_w2   = (u16*)p; p += (size_t)28311552*2;
  u16* c_b2   = (u16*)p; p += (size_t)9216*2;
  u16* c_lnfs = (u16*)p; p += (size_t)768*2;
  u16* c_lnfb = (u16*)p; p += (size_t)768*2;
  float* h = (float*)p; p += (size_t)BT_*D_*4;
  u16* y   = (u16*)p;   p += (size_t)BT_*D_*2;
  u16* qb  = (u16*)p;   p += (size_t)BT_*D_*2;
  u16* kb  = (u16*)p;   p += (size_t)BT_*D_*2;
  u16* vtb = (u16*)p;   p += (size_t)BT_*D_*2;
  u16* ub  = (u16*)p;   p += (size_t)BT_*F_*2;
  u16* att = y;  // attn output reuses y (y dead after QKV gemm, rewritten by ln2)

  detect_k<<<1, 256, 0, stream>>>((const u16*)d_in[8], flag);

  auto cv = [&](const void* s, u16* d, int n){
    int g = (n + 2047) / 2048;
    conv_k<<<g, 256, 0, stream>>>(s, d, n, flag);
  };
  cv(d_in[0],  c_pre,  98304);
  cv(d_in[2],  c_obs,  7864320);
  cv(d_in[4],  c_ro,   491520);
  cv(d_in[6],  c_ln1s, 9216);
  cv(d_in[7],  c_ln1b, 9216);
  cv(d_in[9],  c_bqkv, 27648);
  cv(d_in[11], c_bo,   9216);
  cv(d_in[12], c_ln2s, 9216);
  cv(d_in[13], c_ln2b, 9216);
  cv(d_in[15], c_b1,   36864);
  cv(d_in[17], c_b2,   9216);
  cv(d_in[18], c_lnfs, 768);
  cv(d_in[19], c_lnfb, 768);
  auto cvT = [&](const void* s, u16* d, int Kd, int Nd){
    convT_k<<<dim3(Nd/32, Kd/32, L_), 256, 0, stream>>>(s, d, Kd, Nd, flag);
  };
  cvT(d_in[8],  c_wqkv, D_, 3*D_);
  cvT(d_in[10], c_wo,   D_, D_);
  cvT(d_in[14], c_w1,   D_, F_);
  cvT(d_in[16], c_w2,   F_, D_);

  init_h<<<BT_, 256, 0, stream>>>(c_pre, c_obs, c_ro, h);
  for (int l = 0; l < L_; l++){
    ln_k<<<BT_, 256, 0, stream>>>(h, c_ln1s + l*D_, c_ln1b + l*D_, y);
    gemm_k<0><<<dim3(18,86), 256, 0, stream>>>(y, c_wqkv + (size_t)l*D_*3*D_, c_bqkv + (size_t)l*3*D_,
                                               3*D_, D_, qb, kb, vtb, nullptr, nullptr);
    attn_k<<<dim3(43,96), 64, 0, stream>>>(qb, kb, vtb, att);
    gemm_k<1><<<dim3(6,86), 256, 0, stream>>>(att, c_wo + (size_t)l*D_*D_, c_bo + (size_t)l*D_,
                                              D_, D_, nullptr, nullptr, nullptr, h, nullptr);
    ln_k<<<BT_, 256, 0, stream>>>(h, c_ln2s + l*D_, c_ln2b + l*D_, y);
    gemm_k<2><<<dim3(24,86), 256, 0, stream>>>(y, c_w1 + (size_t)l*D_*F_, c_b1 + (size_t)l*F_,
                                               F_, D_, nullptr, nullptr, nullptr, nullptr, ub);
    gemm_k<1><<<dim3(6,86), 256, 0, stream>>>(ub, c_w2 + (size_t)l*F_*D_, c_b2 + (size_t)l*D_,
                                              D_, F_, nullptr, nullptr, nullptr, h, nullptr);
  }
  ln_out_k<<<BT_, 256, 0, stream>>>(h, c_lnfs, c_lnfb, d_out, flag);
}